// Round 1
// baseline (367.345 us; speedup 1.0000x reference)
//
#include <hip/hip_runtime.h>

#define N_NODES 57254
#define N_EDGES 916064
#define DIM 128
#define NHEAD 8
#define BT (64*512)

typedef __attribute__((ext_vector_type(8))) short short8v;
typedef __attribute__((ext_vector_type(4))) float f32x4;

static __device__ __forceinline__ unsigned short f2bf(float f){
  unsigned int b = __builtin_bit_cast(unsigned int, f);
  b += 0x7fffu + ((b >> 16) & 1u);           // round-to-nearest-even
  return (unsigned short)(b >> 16);
}
static __device__ __forceinline__ float bf2f(unsigned short u){
  unsigned int b = ((unsigned int)u) << 16;
  return __builtin_bit_cast(float, b);
}

// ---------------- CSR build ----------------
__global__ void hist_kernel(const int* __restrict__ dst, int* __restrict__ deg){
  int i = blockIdx.x*256 + threadIdx.x;
  if (i < N_EDGES) atomicAdd(&deg[dst[i]], 1);
}

__global__ void scan_partial(const int* __restrict__ deg, int* __restrict__ offs,
                             int* __restrict__ bsum){
  __shared__ int sm[256];
  int tid = threadIdx.x;
  int i = blockIdx.x*256 + tid;
  int v = (i < N_NODES) ? deg[i] : 0;
  sm[tid] = v;
  __syncthreads();
  #pragma unroll
  for (int d = 1; d < 256; d <<= 1){
    int add = (tid >= d) ? sm[tid - d] : 0;
    __syncthreads();
    sm[tid] += add;
    __syncthreads();
  }
  if (i < N_NODES) offs[i] = sm[tid] - v;          // exclusive within block
  if (tid == 255) bsum[blockIdx.x] = sm[255];      // block total
}

__global__ void scan_top(const int* __restrict__ bsum, int* __restrict__ bbase,
                         int* __restrict__ offs, int nb){
  __shared__ int sm[256];
  int tid = threadIdx.x;
  int v = (tid < nb) ? bsum[tid] : 0;
  sm[tid] = v;
  __syncthreads();
  #pragma unroll
  for (int d = 1; d < 256; d <<= 1){
    int add = (tid >= d) ? sm[tid - d] : 0;
    __syncthreads();
    sm[tid] += add;
    __syncthreads();
  }
  if (tid < nb) bbase[tid] = sm[tid] - v;
  if (tid == 255) offs[N_NODES] = sm[255];         // == E
}

__global__ void scan_add(int* __restrict__ offs, const int* __restrict__ bbase){
  int i = blockIdx.x*256 + threadIdx.x;
  if (i < N_NODES) offs[i] += bbase[blockIdx.x];
}

__global__ void scatter_kernel(const int* __restrict__ src, const int* __restrict__ dst,
                               const int* __restrict__ off, int* __restrict__ cur,
                               int* __restrict__ csr){
  int i = blockIdx.x*256 + threadIdx.x;
  if (i < N_EDGES){
    int d = dst[i];
    int slot = atomicAdd(&cur[d], 1);
    csr[off[d] + slot] = src[i];
  }
}

// ---------------- W transpose -> bf16 Wt[c][k] ----------------
__global__ void twt_kernel(const float* __restrict__ W, unsigned short* __restrict__ Wt){
  int t = blockIdx.x*256 + threadIdx.x;   // t = c*128 + k
  int c = t >> 7, k = t & 127;
  Wt[t] = f2bf(W[k*128 + c]);
}

// ---------------- GEMM: Z(bf16) = A(f32, optionally row-gathered) @ W ----------------
// 128x128 tile per block, K=128 single shot, 4 waves, mfma_f32_16x16x32_bf16.
// LDS tiles XOR-swizzled (byte ^= (row&7)<<4) to kill ds_read_b128 bank conflicts.
__global__ __launch_bounds__(256) void gemm_nt(
    const float* __restrict__ A, const int* __restrict__ gidx,
    const unsigned short* __restrict__ Wt,   // bf16 [col][k]
    unsigned short* __restrict__ Z)          // bf16 [N][128]
{
  __shared__ unsigned short As[128*128];
  __shared__ unsigned short Bs[128*128];
  int t = threadIdx.x;
  int brow = blockIdx.x * 128;
  {
    int r = t >> 1, half = t & 1;
    int grow = brow + r;
    bool valid = grow < N_NODES;
    long srcr = valid ? (gidx ? (long)gidx[grow] : (long)grow) : 0;
    const float* arow = A + srcr * DIM;
    #pragma unroll
    for (int j = 0; j < 8; ++j){
      int c = half*64 + j*8;
      float4 a0, a1;
      if (valid){ a0 = *(const float4*)(arow + c); a1 = *(const float4*)(arow + c + 4); }
      else { a0 = make_float4(0.f,0.f,0.f,0.f); a1 = a0; }
      short8v pk;
      pk[0]=(short)f2bf(a0.x); pk[1]=(short)f2bf(a0.y); pk[2]=(short)f2bf(a0.z); pk[3]=(short)f2bf(a0.w);
      pk[4]=(short)f2bf(a1.x); pk[5]=(short)f2bf(a1.y); pk[6]=(short)f2bf(a1.z); pk[7]=(short)f2bf(a1.w);
      int byte = (r*256 + c*2) ^ ((r & 7) << 4);
      *(short8v*)((char*)As + byte) = pk;
    }
    int cc = t >> 1, khalf = t & 1;
    #pragma unroll
    for (int j = 0; j < 8; ++j){
      int k0 = khalf*64 + j*8;
      short8v w = *(const short8v*)(Wt + cc*128 + k0);
      int byte = (cc*256 + k0*2) ^ ((cc & 7) << 4);
      *(short8v*)((char*)Bs + byte) = w;
    }
  }
  __syncthreads();
  int w = t >> 6, lane = t & 63;
  f32x4 acc[2][8];
  #pragma unroll
  for (int m=0;m<2;m++)
    #pragma unroll
    for (int n=0;n<8;n++) acc[m][n] = (f32x4){0.f,0.f,0.f,0.f};
  #pragma unroll
  for (int kk = 0; kk < 4; ++kk){
    int ks = kk*32 + (lane>>4)*8;
    short8v a[2], b[8];
    #pragma unroll
    for (int m=0;m<2;m++){
      int row = w*32 + m*16 + (lane & 15);
      int byte = (row*256 + ks*2) ^ ((row & 7) << 4);
      a[m] = *(const short8v*)((const char*)As + byte);
    }
    #pragma unroll
    for (int n=0;n<8;n++){
      int col = n*16 + (lane & 15);
      int byte = (col*256 + ks*2) ^ ((col & 7) << 4);
      b[n] = *(const short8v*)((const char*)Bs + byte);
    }
    #pragma unroll
    for (int m=0;m<2;m++)
      #pragma unroll
      for (int n=0;n<8;n++)
        acc[m][n] = __builtin_amdgcn_mfma_f32_16x16x32_bf16(a[m], b[n], acc[m][n], 0, 0, 0);
  }
  #pragma unroll
  for (int m=0;m<2;m++){
    int row_base = brow + w*32 + m*16 + ((lane>>4)<<2);
    #pragma unroll
    for (int r=0;r<4;r++){
      int grow = row_base + r;
      if (grow < N_NODES){
        #pragma unroll
        for (int n=0;n<8;n++)
          Z[(size_t)grow*128 + n*16 + (lane&15)] = f2bf(acc[m][n][r]);
      }
    }
  }
}

// ---------------- el/er: per (node, head) dot over O=16 ----------------
__global__ void eler_kernel(const unsigned short* __restrict__ Z,
                            const float* __restrict__ al, const float* __restrict__ ar,
                            float* __restrict__ el, float* __restrict__ er)
{
  int t = blockIdx.x*256 + threadIdx.x;
  if (t >= N_NODES*NHEAD) return;
  int h = t & 7;
  const unsigned short* zp = Z + (size_t)(t>>3)*128 + h*16;
  short8v z0 = *(const short8v*)(zp);
  short8v z1 = *(const short8v*)(zp + 8);
  float sl = 0.f, sr = 0.f;
  #pragma unroll
  for (int o = 0; o < 8; ++o){
    float zv = bf2f((unsigned short)z0[o]);
    sl += zv * al[h*16+o]; sr += zv * ar[h*16+o];
  }
  #pragma unroll
  for (int o = 0; o < 8; ++o){
    float zv = bf2f((unsigned short)z1[o]);
    sl += zv * al[h*16+8+o]; sr += zv * ar[h*16+8+o];
  }
  el[t] = sl; er[t] = sr;
}

// ---------------- per-node attention aggregate + residual + bias (+act) ----------------
// one wave per node; lane owns dims 2l,2l+1; head = lane>>3; no atomics.
__global__ __launch_bounds__(256) void edge_agg(
    const unsigned short* __restrict__ Z, const float* __restrict__ el,
    const float* __restrict__ er, const int* __restrict__ off,
    const int* __restrict__ csr, const float* __restrict__ Hin,
    const int* __restrict__ gidx, const float* __restrict__ bias,
    float* __restrict__ Hout, int activate)
{
  int n = blockIdx.x*4 + (threadIdx.x >> 6);
  if (n >= N_NODES) return;
  int lane = threadIdx.x & 63;
  int head = lane >> 3;
  float ern = er[n*8 + head];
  int lo = off[n], hi = off[n+1];
  float acc0 = 0.f, acc1 = 0.f, sacc = 0.f;
  for (int e = lo; e < hi; ++e){
    int s = csr[e];
    float xv = el[s*8 + head] + ern;
    xv = (xv > 0.f) ? xv : 0.2f * xv;            // leaky_relu 0.2
    float wgt = __expf(xv);                      // max-shift dropped: |e| << 1
    sacc += wgt;
    unsigned int zz = *(const unsigned int*)(Z + (size_t)s*128 + lane*2);
    acc0 += wgt * bf2f((unsigned short)(zz & 0xffffu));
    acc1 += wgt * __builtin_bit_cast(float, zz & 0xffff0000u);
  }
  float inv = (hi > lo) ? (1.f / sacc) : 0.f;
  long hrow = gidx ? (long)gidx[n] : (long)n;
  int d = lane*2;
  float h0 = Hin[hrow*128 + d], h1v = Hin[hrow*128 + d + 1];
  float r0 = acc0*inv + h0 + bias[d];
  float r1 = acc1*inv + h1v + bias[d+1];
  if (activate){
    r0 = (r0 > 0.f) ? r0 : 0.01f*r0;
    r1 = (r1 > 0.f) ? r1 : 0.01f*r1;
  }
  Hout[(size_t)n*128 + d]     = r0;
  Hout[(size_t)n*128 + d + 1] = r1;
}

// ---------------- L2 normalize + gather out = v[x] ----------------
__global__ __launch_bounds__(256) void norm_gather(const float* __restrict__ H,
    const int* __restrict__ x, float* __restrict__ out)
{
  int row = blockIdx.x*4 + (threadIdx.x >> 6);
  if (row >= BT) return;
  int lane = threadIdx.x & 63;
  long xi = x[row];
  int d = lane*2;
  float v0 = H[xi*128 + d], v1 = H[xi*128 + d + 1];
  float ss = v0*v0 + v1*v1;
  #pragma unroll
  for (int m = 32; m; m >>= 1) ss += __shfl_xor(ss, m, 64);
  float sc = 1.f / fmaxf(sqrtf(ss), 1e-5f);
  out[(size_t)row*128 + d]     = v0*sc;
  out[(size_t)row*128 + d + 1] = v1*sc;
}

extern "C" void kernel_launch(void* const* d_in, const int* in_sizes, int n_in,
                              void* d_out, int out_size, void* d_ws, size_t ws_size,
                              hipStream_t stream)
{
  const float* emb = (const float*)d_in[0];
  const float* W0  = (const float*)d_in[1];
  const float* al0 = (const float*)d_in[2];
  const float* ar0 = (const float*)d_in[3];
  const float* b0  = (const float*)d_in[4];
  const float* W1  = (const float*)d_in[5];
  const float* al1 = (const float*)d_in[6];
  const float* ar1 = (const float*)d_in[7];
  const float* b1  = (const float*)d_in[8];
  const int* n_feat = (const int*)d_in[9];
  const int* srcv = (const int*)d_in[10];
  const int* dstv = (const int*)d_in[11];
  const int* xv   = (const int*)d_in[12];
  float* out = (float*)d_out;

  char* p = (char*)d_ws;
  auto alloc = [&](size_t b)->char*{ char* q = p; p += (b + 255) & ~(size_t)255; return q; };
  unsigned short* Z   = (unsigned short*)alloc((size_t)N_NODES*128*2);
  float* H1  = (float*)alloc((size_t)N_NODES*128*4);
  float* H2  = (float*)alloc((size_t)N_NODES*128*4);
  float* el  = (float*)alloc((size_t)N_NODES*8*4);
  float* er  = (float*)alloc((size_t)N_NODES*8*4);
  int* deg   = (int*)alloc((size_t)N_NODES*4);
  int* cur   = (int*)alloc((size_t)N_NODES*4);
  int* offs  = (int*)alloc((size_t)(N_NODES+1)*4);
  int* csr   = (int*)alloc((size_t)N_EDGES*4);
  int* bsum  = (int*)alloc(256*4);
  int* bbase = (int*)alloc(256*4);
  unsigned short* Wt0 = (unsigned short*)alloc(128*128*2);
  unsigned short* Wt1 = (unsigned short*)alloc(128*128*2);

  hipMemsetAsync(deg, 0, (size_t)N_NODES*4, stream);
  hipMemsetAsync(cur, 0, (size_t)N_NODES*4, stream);

  int nb_scan = (N_NODES + 255)/256;                 // 224 (<=256 required)
  int egrid   = (N_EDGES + 255)/256;

  hist_kernel<<<egrid, 256, 0, stream>>>(dstv, deg);
  scan_partial<<<nb_scan, 256, 0, stream>>>(deg, offs, bsum);
  scan_top<<<1, 256, 0, stream>>>(bsum, bbase, offs, nb_scan);
  scan_add<<<nb_scan, 256, 0, stream>>>(offs, bbase);
  scatter_kernel<<<egrid, 256, 0, stream>>>(srcv, dstv, offs, cur, csr);

  twt_kernel<<<64, 256, 0, stream>>>(W0, Wt0);
  twt_kernel<<<64, 256, 0, stream>>>(W1, Wt1);

  int gemm_grid = (N_NODES + 127)/128;
  int agg_grid  = (N_NODES + 3)/4;
  int eler_grid = (N_NODES*8 + 255)/256;

  // layer 0 (input rows gathered emb[n_feat], activation on)
  gemm_nt<<<gemm_grid, 256, 0, stream>>>(emb, n_feat, Wt0, Z);
  eler_kernel<<<eler_grid, 256, 0, stream>>>(Z, al0, ar0, el, er);
  edge_agg<<<agg_grid, 256, 0, stream>>>(Z, el, er, offs, csr, emb, n_feat, b0, H1, 1);
  // layer 1 (no activation)
  gemm_nt<<<gemm_grid, 256, 0, stream>>>(H1, nullptr, Wt1, Z);
  eler_kernel<<<eler_grid, 256, 0, stream>>>(Z, al1, ar1, el, er);
  edge_agg<<<agg_grid, 256, 0, stream>>>(Z, el, er, offs, csr, H1, nullptr, b1, H2, 0);
  // normalize + output gather
  norm_gather<<<(BT + 3)/4, 256, 0, stream>>>(H2, xv, out);
}

// Round 2
// 297.501 us; speedup vs baseline: 1.2348x; 1.2348x over previous
//
#include <hip/hip_runtime.h>

#define N_NODES 57254
#define N_EDGES 916064
#define DIM 128
#define NHEAD 8
#define BT (64*512)

typedef __attribute__((ext_vector_type(8))) short short8v;
typedef __attribute__((ext_vector_type(4))) float f32x4;

static __device__ __forceinline__ unsigned short f2bf(float f){
  unsigned int b = __builtin_bit_cast(unsigned int, f);
  b += 0x7fffu + ((b >> 16) & 1u);           // round-to-nearest-even
  return (unsigned short)(b >> 16);
}
static __device__ __forceinline__ float bf2f(unsigned short u){
  unsigned int b = ((unsigned int)u) << 16;
  return __builtin_bit_cast(float, b);
}

// ---------------- CSR build ----------------
__global__ void hist_kernel(const int* __restrict__ dst, int* __restrict__ deg){
  int i = blockIdx.x*256 + threadIdx.x;
  if (i < N_EDGES) atomicAdd(&deg[dst[i]], 1);
}

__global__ void scan_partial(const int* __restrict__ deg, int* __restrict__ offs,
                             int* __restrict__ bsum){
  __shared__ int sm[256];
  int tid = threadIdx.x;
  int i = blockIdx.x*256 + tid;
  int v = (i < N_NODES) ? deg[i] : 0;
  sm[tid] = v;
  __syncthreads();
  #pragma unroll
  for (int d = 1; d < 256; d <<= 1){
    int add = (tid >= d) ? sm[tid - d] : 0;
    __syncthreads();
    sm[tid] += add;
    __syncthreads();
  }
  if (i < N_NODES) offs[i] = sm[tid] - v;          // exclusive within block
  if (tid == 255) bsum[blockIdx.x] = sm[255];      // block total
}

__global__ void scan_top(const int* __restrict__ bsum, int* __restrict__ bbase,
                         int* __restrict__ offs, int nb){
  __shared__ int sm[256];
  int tid = threadIdx.x;
  int v = (tid < nb) ? bsum[tid] : 0;
  sm[tid] = v;
  __syncthreads();
  #pragma unroll
  for (int d = 1; d < 256; d <<= 1){
    int add = (tid >= d) ? sm[tid - d] : 0;
    __syncthreads();
    sm[tid] += add;
    __syncthreads();
  }
  if (tid < nb) bbase[tid] = sm[tid] - v;
  if (tid == 255) offs[N_NODES] = sm[255];         // == E
}

__global__ void scan_add(int* __restrict__ offs, const int* __restrict__ bbase){
  int i = blockIdx.x*256 + threadIdx.x;
  if (i < N_NODES) offs[i] += bbase[blockIdx.x];
}

__global__ void scatter_kernel(const int* __restrict__ src, const int* __restrict__ dst,
                               const int* __restrict__ off, int* __restrict__ cur,
                               int* __restrict__ csr){
  int i = blockIdx.x*256 + threadIdx.x;
  if (i < N_EDGES){
    int d = dst[i];
    int slot = atomicAdd(&cur[d], 1);
    csr[off[d] + slot] = src[i];
  }
}

// ---------------- W transpose -> bf16 Wt[c][k] ----------------
__global__ void twt_kernel(const float* __restrict__ W, unsigned short* __restrict__ Wt){
  int t = blockIdx.x*256 + threadIdx.x;   // t = c*128 + k
  int c = t >> 7, k = t & 127;
  Wt[t] = f2bf(W[k*128 + c]);
}

// ---------------- GEMM: Z(bf16) = A(f32, optionally row-gathered) @ W ----------------
__global__ __launch_bounds__(256) void gemm_nt(
    const float* __restrict__ A, const int* __restrict__ gidx,
    const unsigned short* __restrict__ Wt,   // bf16 [col][k]
    unsigned short* __restrict__ Z)          // bf16 [N][128]
{
  __shared__ unsigned short As[128*128];
  __shared__ unsigned short Bs[128*128];
  int t = threadIdx.x;
  int brow = blockIdx.x * 128;
  {
    int r = t >> 1, half = t & 1;
    int grow = brow + r;
    bool valid = grow < N_NODES;
    long srcr = valid ? (gidx ? (long)gidx[grow] : (long)grow) : 0;
    const float* arow = A + srcr * DIM;
    #pragma unroll
    for (int j = 0; j < 8; ++j){
      int c = half*64 + j*8;
      float4 a0, a1;
      if (valid){ a0 = *(const float4*)(arow + c); a1 = *(const float4*)(arow + c + 4); }
      else { a0 = make_float4(0.f,0.f,0.f,0.f); a1 = a0; }
      short8v pk;
      pk[0]=(short)f2bf(a0.x); pk[1]=(short)f2bf(a0.y); pk[2]=(short)f2bf(a0.z); pk[3]=(short)f2bf(a0.w);
      pk[4]=(short)f2bf(a1.x); pk[5]=(short)f2bf(a1.y); pk[6]=(short)f2bf(a1.z); pk[7]=(short)f2bf(a1.w);
      int byte = (r*256 + c*2) ^ ((r & 7) << 4);
      *(short8v*)((char*)As + byte) = pk;
    }
    int cc = t >> 1, khalf = t & 1;
    #pragma unroll
    for (int j = 0; j < 8; ++j){
      int k0 = khalf*64 + j*8;
      short8v w = *(const short8v*)(Wt + cc*128 + k0);
      int byte = (cc*256 + k0*2) ^ ((cc & 7) << 4);
      *(short8v*)((char*)Bs + byte) = w;
    }
  }
  __syncthreads();
  int w = t >> 6, lane = t & 63;
  f32x4 acc[2][8];
  #pragma unroll
  for (int m=0;m<2;m++)
    #pragma unroll
    for (int n=0;n<8;n++) acc[m][n] = (f32x4){0.f,0.f,0.f,0.f};
  #pragma unroll
  for (int kk = 0; kk < 4; ++kk){
    int ks = kk*32 + (lane>>4)*8;
    short8v a[2], b[8];
    #pragma unroll
    for (int m=0;m<2;m++){
      int row = w*32 + m*16 + (lane & 15);
      int byte = (row*256 + ks*2) ^ ((row & 7) << 4);
      a[m] = *(const short8v*)((const char*)As + byte);
    }
    #pragma unroll
    for (int n=0;n<8;n++){
      int col = n*16 + (lane & 15);
      int byte = (col*256 + ks*2) ^ ((col & 7) << 4);
      b[n] = *(const short8v*)((const char*)Bs + byte);
    }
    #pragma unroll
    for (int m=0;m<2;m++)
      #pragma unroll
      for (int n=0;n<8;n++)
        acc[m][n] = __builtin_amdgcn_mfma_f32_16x16x32_bf16(a[m], b[n], acc[m][n], 0, 0, 0);
  }
  #pragma unroll
  for (int m=0;m<2;m++){
    int row_base = brow + w*32 + m*16 + ((lane>>4)<<2);
    #pragma unroll
    for (int r=0;r<4;r++){
      int grow = row_base + r;
      if (grow < N_NODES){
        #pragma unroll
        for (int n=0;n<8;n++)
          Z[(size_t)grow*128 + n*16 + (lane&15)] = f2bf(acc[m][n][r]);
      }
    }
  }
}

// ---------------- el/er: per (node, head) dot over O=16 ----------------
__global__ void eler_kernel(const unsigned short* __restrict__ Z,
                            const float* __restrict__ al, const float* __restrict__ ar,
                            float* __restrict__ el, float* __restrict__ er)
{
  int t = blockIdx.x*256 + threadIdx.x;
  if (t >= N_NODES*NHEAD) return;
  int h = t & 7;
  const unsigned short* zp = Z + (size_t)(t>>3)*128 + h*16;
  short8v z0 = *(const short8v*)(zp);
  short8v z1 = *(const short8v*)(zp + 8);
  float sl = 0.f, sr = 0.f;
  #pragma unroll
  for (int o = 0; o < 8; ++o){
    float zv = bf2f((unsigned short)z0[o]);
    sl += zv * al[h*16+o]; sr += zv * ar[h*16+o];
  }
  #pragma unroll
  for (int o = 0; o < 8; ++o){
    float zv = bf2f((unsigned short)z1[o]);
    sl += zv * al[h*16+8+o]; sr += zv * ar[h*16+8+o];
  }
  el[t] = sl; er[t] = sr;
}

// ---------------- per-node attention aggregate + residual + bias (+act) ----------------
// 2 waves per node (interleaved quads), 4-wide unrolled edge loop, LDS combine.
__global__ __launch_bounds__(256) void edge_agg(
    const unsigned short* __restrict__ Z, const float* __restrict__ el,
    const float* __restrict__ er, const int* __restrict__ off,
    const int* __restrict__ csr, const float* __restrict__ Hin,
    const int* __restrict__ gidx, const float* __restrict__ bias,
    float* __restrict__ Hout, int activate)
{
  __shared__ float red[4][64][3];
  int wid  = threadIdx.x >> 6;          // 0..3
  int half = wid & 1;                   // which of the node's 2 waves
  int n = blockIdx.x*2 + (wid >> 1);
  int lane = threadIdx.x & 63;
  int head = lane >> 3;

  float acc0 = 0.f, acc1 = 0.f, sacc = 0.f;
  int lo = 0, hi = 0;
  float ern = 0.f;
  if (n < N_NODES){
    lo = off[n]; hi = off[n+1];
    ern = er[n*8 + head];
    // interleaved quads: wave `half` owns quads {half, half+2, half+4, ...}
    for (int base = lo + half*4; base < hi; base += 8){
      int m = hi - base; if (m > 4) m = 4;
      if (m == 4){
        int s0 = csr[base], s1 = csr[base+1], s2 = csr[base+2], s3 = csr[base+3];
        float x0 = el[s0*8+head] + ern;
        float x1 = el[s1*8+head] + ern;
        float x2 = el[s2*8+head] + ern;
        float x3 = el[s3*8+head] + ern;
        unsigned int zz0 = *(const unsigned int*)(Z + (size_t)s0*128 + lane*2);
        unsigned int zz1 = *(const unsigned int*)(Z + (size_t)s1*128 + lane*2);
        unsigned int zz2 = *(const unsigned int*)(Z + (size_t)s2*128 + lane*2);
        unsigned int zz3 = *(const unsigned int*)(Z + (size_t)s3*128 + lane*2);
        x0 = (x0 > 0.f) ? x0 : 0.2f*x0;
        x1 = (x1 > 0.f) ? x1 : 0.2f*x1;
        x2 = (x2 > 0.f) ? x2 : 0.2f*x2;
        x3 = (x3 > 0.f) ? x3 : 0.2f*x3;
        float w0 = __expf(x0), w1 = __expf(x1), w2 = __expf(x2), w3 = __expf(x3);
        sacc += (w0 + w1) + (w2 + w3);
        acc0 += w0 * bf2f((unsigned short)(zz0 & 0xffffu));
        acc1 += w0 * __builtin_bit_cast(float, zz0 & 0xffff0000u);
        acc0 += w1 * bf2f((unsigned short)(zz1 & 0xffffu));
        acc1 += w1 * __builtin_bit_cast(float, zz1 & 0xffff0000u);
        acc0 += w2 * bf2f((unsigned short)(zz2 & 0xffffu));
        acc1 += w2 * __builtin_bit_cast(float, zz2 & 0xffff0000u);
        acc0 += w3 * bf2f((unsigned short)(zz3 & 0xffffu));
        acc1 += w3 * __builtin_bit_cast(float, zz3 & 0xffff0000u);
      } else {
        for (int j = 0; j < m; ++j){
          int s = csr[base + j];
          float xv = el[s*8+head] + ern;
          xv = (xv > 0.f) ? xv : 0.2f*xv;
          float wgt = __expf(xv);
          sacc += wgt;
          unsigned int zz = *(const unsigned int*)(Z + (size_t)s*128 + lane*2);
          acc0 += wgt * bf2f((unsigned short)(zz & 0xffffu));
          acc1 += wgt * __builtin_bit_cast(float, zz & 0xffff0000u);
        }
      }
    }
  }
  red[wid][lane][0] = acc0;
  red[wid][lane][1] = acc1;
  red[wid][lane][2] = sacc;
  __syncthreads();
  if (half == 0 && n < N_NODES){
    acc0 += red[wid+1][lane][0];
    acc1 += red[wid+1][lane][1];
    sacc += red[wid+1][lane][2];
    float inv = (hi > lo) ? (1.f / sacc) : 0.f;
    long hrow = gidx ? (long)gidx[n] : (long)n;
    int d = lane*2;
    float h0 = Hin[hrow*128 + d], h1v = Hin[hrow*128 + d + 1];
    float r0 = acc0*inv + h0 + bias[d];
    float r1 = acc1*inv + h1v + bias[d+1];
    if (activate){
      r0 = (r0 > 0.f) ? r0 : 0.01f*r0;
      r1 = (r1 > 0.f) ? r1 : 0.01f*r1;
    }
    Hout[(size_t)n*128 + d]     = r0;
    Hout[(size_t)n*128 + d + 1] = r1;
  }
}

// ---------------- L2 normalize + gather out = v[x] ----------------
__global__ __launch_bounds__(256) void norm_gather(const float* __restrict__ H,
    const int* __restrict__ x, float* __restrict__ out)
{
  int row = blockIdx.x*4 + (threadIdx.x >> 6);
  if (row >= BT) return;
  int lane = threadIdx.x & 63;
  long xi = x[row];
  int d = lane*2;
  float v0 = H[xi*128 + d], v1 = H[xi*128 + d + 1];
  float ss = v0*v0 + v1*v1;
  #pragma unroll
  for (int m = 32; m; m >>= 1) ss += __shfl_xor(ss, m, 64);
  float sc = 1.f / fmaxf(sqrtf(ss), 1e-5f);
  out[(size_t)row*128 + d]     = v0*sc;
  out[(size_t)row*128 + d + 1] = v1*sc;
}

extern "C" void kernel_launch(void* const* d_in, const int* in_sizes, int n_in,
                              void* d_out, int out_size, void* d_ws, size_t ws_size,
                              hipStream_t stream)
{
  const float* emb = (const float*)d_in[0];
  const float* W0  = (const float*)d_in[1];
  const float* al0 = (const float*)d_in[2];
  const float* ar0 = (const float*)d_in[3];
  const float* b0  = (const float*)d_in[4];
  const float* W1  = (const float*)d_in[5];
  const float* al1 = (const float*)d_in[6];
  const float* ar1 = (const float*)d_in[7];
  const float* b1  = (const float*)d_in[8];
  const int* n_feat = (const int*)d_in[9];
  const int* srcv = (const int*)d_in[10];
  const int* dstv = (const int*)d_in[11];
  const int* xv   = (const int*)d_in[12];
  float* out = (float*)d_out;

  char* p = (char*)d_ws;
  auto alloc = [&](size_t b)->char*{ char* q = p; p += (b + 255) & ~(size_t)255; return q; };
  unsigned short* Z   = (unsigned short*)alloc((size_t)N_NODES*128*2);
  float* H1  = (float*)alloc((size_t)N_NODES*128*4);
  float* H2  = (float*)alloc((size_t)N_NODES*128*4);
  float* el  = (float*)alloc((size_t)N_NODES*8*4);
  float* er  = (float*)alloc((size_t)N_NODES*8*4);
  int* deg   = (int*)alloc((size_t)N_NODES*4);
  int* cur   = (int*)alloc((size_t)N_NODES*4);
  int* offs  = (int*)alloc((size_t)(N_NODES+1)*4);
  int* csr   = (int*)alloc((size_t)N_EDGES*4);
  int* bsum  = (int*)alloc(256*4);
  int* bbase = (int*)alloc(256*4);
  unsigned short* Wt0 = (unsigned short*)alloc(128*128*2);
  unsigned short* Wt1 = (unsigned short*)alloc(128*128*2);

  hipMemsetAsync(deg, 0, (size_t)N_NODES*4, stream);
  hipMemsetAsync(cur, 0, (size_t)N_NODES*4, stream);

  int nb_scan = (N_NODES + 255)/256;                 // 224 (<=256 required)
  int egrid   = (N_EDGES + 255)/256;

  hist_kernel<<<egrid, 256, 0, stream>>>(dstv, deg);
  scan_partial<<<nb_scan, 256, 0, stream>>>(deg, offs, bsum);
  scan_top<<<1, 256, 0, stream>>>(bsum, bbase, offs, nb_scan);
  scan_add<<<nb_scan, 256, 0, stream>>>(offs, bbase);
  scatter_kernel<<<egrid, 256, 0, stream>>>(srcv, dstv, offs, cur, csr);

  twt_kernel<<<64, 256, 0, stream>>>(W0, Wt0);
  twt_kernel<<<64, 256, 0, stream>>>(W1, Wt1);

  int gemm_grid = (N_NODES + 127)/128;
  int agg_grid  = (N_NODES + 1)/2;
  int eler_grid = (N_NODES*8 + 255)/256;

  // layer 0 (input rows gathered emb[n_feat], activation on)
  gemm_nt<<<gemm_grid, 256, 0, stream>>>(emb, n_feat, Wt0, Z);
  eler_kernel<<<eler_grid, 256, 0, stream>>>(Z, al0, ar0, el, er);
  edge_agg<<<agg_grid, 256, 0, stream>>>(Z, el, er, offs, csr, emb, n_feat, b0, H1, 1);
  // layer 1 (no activation)
  gemm_nt<<<gemm_grid, 256, 0, stream>>>(H1, nullptr, Wt1, Z);
  eler_kernel<<<eler_grid, 256, 0, stream>>>(Z, al1, ar1, el, er);
  edge_agg<<<agg_grid, 256, 0, stream>>>(Z, el, er, offs, csr, H1, nullptr, b1, H2, 0);
  // normalize + output gather
  norm_gather<<<(BT + 3)/4, 256, 0, stream>>>(H2, xv, out);
}

// Round 3
// 285.741 us; speedup vs baseline: 1.2856x; 1.0412x over previous
//
#include <hip/hip_runtime.h>

#define N_NODES 57254
#define N_EDGES 916064
#define DIM 128
#define NHEAD 8
#define BT (64*512)

typedef __attribute__((ext_vector_type(8))) short short8v;
typedef __attribute__((ext_vector_type(4))) float f32x4;

static __device__ __forceinline__ unsigned short f2bf(float f){
  unsigned int b = __builtin_bit_cast(unsigned int, f);
  b += 0x7fffu + ((b >> 16) & 1u);           // round-to-nearest-even
  return (unsigned short)(b >> 16);
}
static __device__ __forceinline__ float bf2f(unsigned short u){
  unsigned int b = ((unsigned int)u) << 16;
  return __builtin_bit_cast(float, b);
}
static __device__ __forceinline__ float lo16f(unsigned int zz){
  return __builtin_bit_cast(float, zz << 16);
}
static __device__ __forceinline__ float hi16f(unsigned int zz){
  return __builtin_bit_cast(float, zz & 0xffff0000u);
}

// ---------------- CSR build ----------------
__global__ void hist_kernel(const int* __restrict__ dst, int* __restrict__ deg){
  int i = blockIdx.x*256 + threadIdx.x;
  if (i < N_EDGES) atomicAdd(&deg[dst[i]], 1);
}

__global__ void scan_partial(const int* __restrict__ deg, int* __restrict__ offs,
                             int* __restrict__ bsum){
  __shared__ int sm[256];
  int tid = threadIdx.x;
  int i = blockIdx.x*256 + tid;
  int v = (i < N_NODES) ? deg[i] : 0;
  sm[tid] = v;
  __syncthreads();
  #pragma unroll
  for (int d = 1; d < 256; d <<= 1){
    int add = (tid >= d) ? sm[tid - d] : 0;
    __syncthreads();
    sm[tid] += add;
    __syncthreads();
  }
  if (i < N_NODES) offs[i] = sm[tid] - v;          // exclusive within block
  if (tid == 255) bsum[blockIdx.x] = sm[255];      // block total
}

__global__ void scan_top(const int* __restrict__ bsum, int* __restrict__ bbase,
                         int* __restrict__ offs, int nb){
  __shared__ int sm[256];
  int tid = threadIdx.x;
  int v = (tid < nb) ? bsum[tid] : 0;
  sm[tid] = v;
  __syncthreads();
  #pragma unroll
  for (int d = 1; d < 256; d <<= 1){
    int add = (tid >= d) ? sm[tid - d] : 0;
    __syncthreads();
    sm[tid] += add;
    __syncthreads();
  }
  if (tid < nb) bbase[tid] = sm[tid] - v;
  if (tid == 255) offs[N_NODES] = sm[255];         // == E
}

__global__ void scan_add(int* __restrict__ offs, const int* __restrict__ bbase){
  int i = blockIdx.x*256 + threadIdx.x;
  if (i < N_NODES) offs[i] += bbase[blockIdx.x];
}

__global__ void scatter_kernel(const int* __restrict__ src, const int* __restrict__ dst,
                               const int* __restrict__ off, int* __restrict__ cur,
                               int* __restrict__ csr){
  int i = blockIdx.x*256 + threadIdx.x;
  if (i < N_EDGES){
    int d = dst[i];
    int slot = atomicAdd(&cur[d], 1);
    csr[off[d] + slot] = src[i];
  }
}

// ---------------- W transpose -> bf16 Wt[c][k], both layers in one launch ----------------
__global__ void twt_kernel(const float* __restrict__ W0, const float* __restrict__ W1,
                           unsigned short* __restrict__ Wt0, unsigned short* __restrict__ Wt1){
  int t = blockIdx.x*256 + threadIdx.x;   // 0..32767
  int which = t >> 14;
  int i = t & 16383;
  int c = i >> 7, k = i & 127;
  const float* W = which ? W1 : W0;
  unsigned short* Wt = which ? Wt1 : Wt0;
  Wt[i] = f2bf(W[k*128 + c]);
}

// ---------------- GEMM: Z(bf16) = A(f32, optionally row-gathered) @ W ----------------
// BM=64 tile (LDS 48KB -> 3 blocks/CU, 12 waves/CU for gather latency hiding).
__global__ __launch_bounds__(256) void gemm_nt(
    const float* __restrict__ A, const int* __restrict__ gidx,
    const unsigned short* __restrict__ Wt,   // bf16 [col][k]
    unsigned short* __restrict__ Z)          // bf16 [N][128]
{
  __shared__ unsigned short As[64*128];      // 16KB
  __shared__ unsigned short Bs[128*128];     // 32KB
  int t = threadIdx.x;
  int brow = blockIdx.x * 64;
  {
    int r = t >> 2, q = t & 3;               // 4 threads per row, 32 cols each
    int grow = brow + r;
    bool valid = grow < N_NODES;
    unsigned srcr = valid ? (gidx ? (unsigned)gidx[grow] : (unsigned)grow) : 0u;
    const float* arow = A + (size_t)srcr * DIM;
    #pragma unroll
    for (int j = 0; j < 4; ++j){
      int c = q*32 + j*8;
      float4 a0, a1;
      if (valid){ a0 = *(const float4*)(arow + c); a1 = *(const float4*)(arow + c + 4); }
      else { a0 = make_float4(0.f,0.f,0.f,0.f); a1 = a0; }
      short8v pk;
      pk[0]=(short)f2bf(a0.x); pk[1]=(short)f2bf(a0.y); pk[2]=(short)f2bf(a0.z); pk[3]=(short)f2bf(a0.w);
      pk[4]=(short)f2bf(a1.x); pk[5]=(short)f2bf(a1.y); pk[6]=(short)f2bf(a1.z); pk[7]=(short)f2bf(a1.w);
      int byte = (r*256 + c*2) ^ ((r & 7) << 4);
      *(short8v*)((char*)As + byte) = pk;
    }
    int cc = t >> 1, khalf = t & 1;
    #pragma unroll
    for (int j = 0; j < 8; ++j){
      int k0 = khalf*64 + j*8;
      short8v w = *(const short8v*)(Wt + cc*128 + k0);
      int byte = (cc*256 + k0*2) ^ ((cc & 7) << 4);
      *(short8v*)((char*)Bs + byte) = w;
    }
  }
  __syncthreads();
  int w = t >> 6, lane = t & 63;
  f32x4 acc[8];
  #pragma unroll
  for (int n=0;n<8;n++) acc[n] = (f32x4){0.f,0.f,0.f,0.f};
  #pragma unroll
  for (int kk = 0; kk < 4; ++kk){
    int ks = kk*32 + (lane>>4)*8;
    int row = w*16 + (lane & 15);
    int abyte = (row*256 + ks*2) ^ ((row & 7) << 4);
    short8v a = *(const short8v*)((const char*)As + abyte);
    short8v b[8];
    #pragma unroll
    for (int n=0;n<8;n++){
      int col = n*16 + (lane & 15);
      int byte = (col*256 + ks*2) ^ ((col & 7) << 4);
      b[n] = *(const short8v*)((const char*)Bs + byte);
    }
    #pragma unroll
    for (int n=0;n<8;n++)
      acc[n] = __builtin_amdgcn_mfma_f32_16x16x32_bf16(a, b[n], acc[n], 0, 0, 0);
  }
  int row_base = brow + w*16 + ((lane>>4)<<2);
  #pragma unroll
  for (int r=0;r<4;r++){
    int grow = row_base + r;
    if (grow < N_NODES){
      #pragma unroll
      for (int n=0;n<8;n++)
        Z[(unsigned)grow*128u + n*16 + (lane&15)] = f2bf(acc[n][r]);
    }
  }
}

// ---------------- el/er: per (node, head) dot over O=16 ----------------
__global__ void eler_kernel(const unsigned short* __restrict__ Z,
                            const float* __restrict__ al, const float* __restrict__ ar,
                            float* __restrict__ el, float* __restrict__ er)
{
  int t = blockIdx.x*256 + threadIdx.x;
  if (t >= N_NODES*NHEAD) return;
  int h = t & 7;
  const unsigned short* zp = Z + (unsigned)(t>>3)*128u + h*16;
  short8v z0 = *(const short8v*)(zp);
  short8v z1 = *(const short8v*)(zp + 8);
  float sl = 0.f, sr = 0.f;
  #pragma unroll
  for (int o = 0; o < 8; ++o){
    float zv = bf2f((unsigned short)z0[o]);
    sl += zv * al[h*16+o]; sr += zv * ar[h*16+o];
  }
  #pragma unroll
  for (int o = 0; o < 8; ++o){
    float zv = bf2f((unsigned short)z1[o]);
    sl += zv * al[h*16+8+o]; sr += zv * ar[h*16+8+o];
  }
  el[t] = sl; er[t] = sr;
}

// ---------------- per-node attention aggregate + residual + bias (+act) ----------------
// 2 waves per node; SCALARIZED edge walk (s_load csr, saddr-form gathers);
// 8-wide edge batches (16 gathers in flight / wave).
__global__ __launch_bounds__(256) void edge_agg(
    const unsigned short* __restrict__ Z, const float* __restrict__ el,
    const float* __restrict__ er, const int* __restrict__ off,
    const int* __restrict__ csr, const float* __restrict__ Hin,
    const int* __restrict__ gidx, const float* __restrict__ bias,
    float* __restrict__ Hout, int activate)
{
  __shared__ float red[4][64][3];
  int tid  = threadIdx.x;
  int lane = tid & 63;
  int wid  = tid >> 6;
  int n    = __builtin_amdgcn_readfirstlane((int)(blockIdx.x*2 + (tid >> 7)));
  int half = __builtin_amdgcn_readfirstlane(wid & 1);
  int head = lane >> 3;

  int lo = off[n], hi = off[n+1];
  float ern = er[(unsigned)n*8u + head];
  float acc0 = 0.f, acc1 = 0.f, sacc = 0.f;
  const unsigned lidx = (unsigned)(lane*2);          // ushort index within Z row

  for (int base = lo + half*8; base < hi; base += 16){
    int m = hi - base; if (m > 8) m = 8;
    if (m == 8){
      int s0=csr[base+0], s1=csr[base+1], s2=csr[base+2], s3=csr[base+3];
      int s4=csr[base+4], s5=csr[base+5], s6=csr[base+6], s7=csr[base+7];
      float x0 = el[(unsigned)s0*8u+head] + ern;
      float x1 = el[(unsigned)s1*8u+head] + ern;
      float x2 = el[(unsigned)s2*8u+head] + ern;
      float x3 = el[(unsigned)s3*8u+head] + ern;
      float x4 = el[(unsigned)s4*8u+head] + ern;
      float x5 = el[(unsigned)s5*8u+head] + ern;
      float x6 = el[(unsigned)s6*8u+head] + ern;
      float x7 = el[(unsigned)s7*8u+head] + ern;
      unsigned zz0 = *(const unsigned*)(Z + (unsigned)s0*128u + lidx);
      unsigned zz1 = *(const unsigned*)(Z + (unsigned)s1*128u + lidx);
      unsigned zz2 = *(const unsigned*)(Z + (unsigned)s2*128u + lidx);
      unsigned zz3 = *(const unsigned*)(Z + (unsigned)s3*128u + lidx);
      unsigned zz4 = *(const unsigned*)(Z + (unsigned)s4*128u + lidx);
      unsigned zz5 = *(const unsigned*)(Z + (unsigned)s5*128u + lidx);
      unsigned zz6 = *(const unsigned*)(Z + (unsigned)s6*128u + lidx);
      unsigned zz7 = *(const unsigned*)(Z + (unsigned)s7*128u + lidx);
      x0 = fmaxf(x0, 0.2f*x0); x1 = fmaxf(x1, 0.2f*x1);
      x2 = fmaxf(x2, 0.2f*x2); x3 = fmaxf(x3, 0.2f*x3);
      x4 = fmaxf(x4, 0.2f*x4); x5 = fmaxf(x5, 0.2f*x5);
      x6 = fmaxf(x6, 0.2f*x6); x7 = fmaxf(x7, 0.2f*x7);
      float w0=__expf(x0), w1=__expf(x1), w2=__expf(x2), w3=__expf(x3);
      float w4=__expf(x4), w5=__expf(x5), w6=__expf(x6), w7=__expf(x7);
      sacc += ((w0+w1)+(w2+w3)) + ((w4+w5)+(w6+w7));
      acc0 += w0*lo16f(zz0); acc1 += w0*hi16f(zz0);
      acc0 += w1*lo16f(zz1); acc1 += w1*hi16f(zz1);
      acc0 += w2*lo16f(zz2); acc1 += w2*hi16f(zz2);
      acc0 += w3*lo16f(zz3); acc1 += w3*hi16f(zz3);
      acc0 += w4*lo16f(zz4); acc1 += w4*hi16f(zz4);
      acc0 += w5*lo16f(zz5); acc1 += w5*hi16f(zz5);
      acc0 += w6*lo16f(zz6); acc1 += w6*hi16f(zz6);
      acc0 += w7*lo16f(zz7); acc1 += w7*hi16f(zz7);
    } else {
      for (int j = 0; j < m; ++j){
        int s = csr[base + j];
        float xv = el[(unsigned)s*8u+head] + ern;
        xv = fmaxf(xv, 0.2f*xv);
        float wgt = __expf(xv);
        sacc += wgt;
        unsigned zz = *(const unsigned*)(Z + (unsigned)s*128u + lidx);
        acc0 += wgt*lo16f(zz); acc1 += wgt*hi16f(zz);
      }
    }
  }
  red[wid][lane][0] = acc0;
  red[wid][lane][1] = acc1;
  red[wid][lane][2] = sacc;
  __syncthreads();
  if (half == 0){
    acc0 += red[wid+1][lane][0];
    acc1 += red[wid+1][lane][1];
    sacc += red[wid+1][lane][2];
    float inv = (hi > lo) ? (1.f / sacc) : 0.f;
    unsigned hrow = gidx ? (unsigned)gidx[n] : (unsigned)n;
    int d = lane*2;
    float h0 = Hin[hrow*128u + d], h1v = Hin[hrow*128u + d + 1];
    float r0 = acc0*inv + h0 + bias[d];
    float r1 = acc1*inv + h1v + bias[d+1];
    if (activate){
      r0 = (r0 > 0.f) ? r0 : 0.01f*r0;
      r1 = (r1 > 0.f) ? r1 : 0.01f*r1;
    }
    Hout[(unsigned)n*128u + d]     = r0;
    Hout[(unsigned)n*128u + d + 1] = r1;
  }
}

// ---------------- L2 normalize + gather out = v[x] ----------------
__global__ __launch_bounds__(256) void norm_gather(const float* __restrict__ H,
    const int* __restrict__ x, float* __restrict__ out)
{
  int row = blockIdx.x*4 + (threadIdx.x >> 6);
  if (row >= BT) return;
  int lane = threadIdx.x & 63;
  unsigned xi = (unsigned)x[row];
  int d = lane*2;
  float v0 = H[xi*128u + d], v1 = H[xi*128u + d + 1];
  float ss = v0*v0 + v1*v1;
  #pragma unroll
  for (int m = 32; m; m >>= 1) ss += __shfl_xor(ss, m, 64);
  float sc = 1.f / fmaxf(sqrtf(ss), 1e-5f);
  out[(size_t)row*128 + d]     = v0*sc;
  out[(size_t)row*128 + d + 1] = v1*sc;
}

extern "C" void kernel_launch(void* const* d_in, const int* in_sizes, int n_in,
                              void* d_out, int out_size, void* d_ws, size_t ws_size,
                              hipStream_t stream)
{
  const float* emb = (const float*)d_in[0];
  const float* W0  = (const float*)d_in[1];
  const float* al0 = (const float*)d_in[2];
  const float* ar0 = (const float*)d_in[3];
  const float* b0  = (const float*)d_in[4];
  const float* W1  = (const float*)d_in[5];
  const float* al1 = (const float*)d_in[6];
  const float* ar1 = (const float*)d_in[7];
  const float* b1  = (const float*)d_in[8];
  const int* n_feat = (const int*)d_in[9];
  const int* srcv = (const int*)d_in[10];
  const int* dstv = (const int*)d_in[11];
  const int* xv   = (const int*)d_in[12];
  float* out = (float*)d_out;

  char* p = (char*)d_ws;
  auto alloc = [&](size_t b)->char*{ char* q = p; p += (b + 255) & ~(size_t)255; return q; };
  unsigned short* Z   = (unsigned short*)alloc((size_t)N_NODES*128*2);
  float* H1  = (float*)alloc((size_t)N_NODES*128*4);
  float* H2  = (float*)alloc((size_t)N_NODES*128*4);
  float* el  = (float*)alloc((size_t)N_NODES*8*4);
  float* er  = (float*)alloc((size_t)N_NODES*8*4);
  int* deg   = (int*)alloc((size_t)N_NODES*4);
  int* cur   = (int*)alloc((size_t)N_NODES*4);
  int* offs  = (int*)alloc((size_t)(N_NODES+1)*4);
  int* csr   = (int*)alloc((size_t)N_EDGES*4);
  int* bsum  = (int*)alloc(256*4);
  int* bbase = (int*)alloc(256*4);
  unsigned short* Wt0 = (unsigned short*)alloc(128*128*2);
  unsigned short* Wt1 = (unsigned short*)alloc(128*128*2);

  hipMemsetAsync(deg, 0, (size_t)N_NODES*4, stream);
  hipMemsetAsync(cur, 0, (size_t)N_NODES*4, stream);

  int nb_scan = (N_NODES + 255)/256;                 // 224 (<=256 required)
  int egrid   = (N_EDGES + 255)/256;

  hist_kernel<<<egrid, 256, 0, stream>>>(dstv, deg);
  scan_partial<<<nb_scan, 256, 0, stream>>>(deg, offs, bsum);
  scan_top<<<1, 256, 0, stream>>>(bsum, bbase, offs, nb_scan);
  scan_add<<<nb_scan, 256, 0, stream>>>(offs, bbase);
  scatter_kernel<<<egrid, 256, 0, stream>>>(srcv, dstv, offs, cur, csr);

  twt_kernel<<<128, 256, 0, stream>>>(W0, W1, Wt0, Wt1);

  int gemm_grid = (N_NODES + 63)/64;
  int agg_grid  = (N_NODES + 1)/2;
  int eler_grid = (N_NODES*8 + 255)/256;

  // layer 0 (input rows gathered emb[n_feat], activation on)
  gemm_nt<<<gemm_grid, 256, 0, stream>>>(emb, n_feat, Wt0, Z);
  eler_kernel<<<eler_grid, 256, 0, stream>>>(Z, al0, ar0, el, er);
  edge_agg<<<agg_grid, 256, 0, stream>>>(Z, el, er, offs, csr, emb, n_feat, b0, H1, 1);
  // layer 1 (no activation)
  gemm_nt<<<gemm_grid, 256, 0, stream>>>(H1, nullptr, Wt1, Z);
  eler_kernel<<<eler_grid, 256, 0, stream>>>(Z, al1, ar1, el, er);
  edge_agg<<<agg_grid, 256, 0, stream>>>(Z, el, er, offs, csr, H1, nullptr, b1, H2, 0);
  // normalize + output gather
  norm_gather<<<(BT + 3)/4, 256, 0, stream>>>(H2, xv, out);
}

// Round 4
// 279.676 us; speedup vs baseline: 1.3135x; 1.0217x over previous
//
#include <hip/hip_runtime.h>

#define N_NODES 57254
#define N_EDGES 916064
#define DIM 128
#define NHEAD 8
#define BT (64*512)

typedef __attribute__((ext_vector_type(8))) short short8v;
typedef __attribute__((ext_vector_type(4))) float f32x4;

static __device__ __forceinline__ unsigned short f2bf(float f){
  unsigned int b = __builtin_bit_cast(unsigned int, f);
  b += 0x7fffu + ((b >> 16) & 1u);           // round-to-nearest-even
  return (unsigned short)(b >> 16);
}
static __device__ __forceinline__ float bf2f(unsigned short u){
  unsigned int b = ((unsigned int)u) << 16;
  return __builtin_bit_cast(float, b);
}
static __device__ __forceinline__ float lo16f(unsigned int zz){
  return __builtin_bit_cast(float, zz << 16);
}
static __device__ __forceinline__ float hi16f(unsigned int zz){
  return __builtin_bit_cast(float, zz & 0xffff0000u);
}

// ---------------- CSR build ----------------
__global__ void hist_kernel(const int* __restrict__ dst, int* __restrict__ deg){
  int i = blockIdx.x*256 + threadIdx.x;
  if (i < N_EDGES) atomicAdd(&deg[dst[i]], 1);
}

__global__ void scan_partial(const int* __restrict__ deg, int* __restrict__ offs,
                             int* __restrict__ bsum){
  __shared__ int sm[256];
  int tid = threadIdx.x;
  int i = blockIdx.x*256 + tid;
  int v = (i < N_NODES) ? deg[i] : 0;
  sm[tid] = v;
  __syncthreads();
  #pragma unroll
  for (int d = 1; d < 256; d <<= 1){
    int add = (tid >= d) ? sm[tid - d] : 0;
    __syncthreads();
    sm[tid] += add;
    __syncthreads();
  }
  if (i < N_NODES) offs[i] = sm[tid] - v;          // exclusive within block
  if (tid == 255) bsum[blockIdx.x] = sm[255];      // block total
}

__global__ void scan_top(const int* __restrict__ bsum, int* __restrict__ bbase,
                         int* __restrict__ offs, int nb){
  __shared__ int sm[256];
  int tid = threadIdx.x;
  int v = (tid < nb) ? bsum[tid] : 0;
  sm[tid] = v;
  __syncthreads();
  #pragma unroll
  for (int d = 1; d < 256; d <<= 1){
    int add = (tid >= d) ? sm[tid - d] : 0;
    __syncthreads();
    sm[tid] += add;
    __syncthreads();
  }
  if (tid < nb) bbase[tid] = sm[tid] - v;
  if (tid == 255) offs[N_NODES] = sm[255];         // == E
}

__global__ void scan_add(int* __restrict__ offs, const int* __restrict__ bbase){
  int i = blockIdx.x*256 + threadIdx.x;
  if (i < N_NODES) offs[i] += bbase[blockIdx.x];
}

__global__ void scatter_kernel(const int* __restrict__ src, const int* __restrict__ dst,
                               const int* __restrict__ off, int* __restrict__ cur,
                               int* __restrict__ csr){
  int i = blockIdx.x*256 + threadIdx.x;
  if (i < N_EDGES){
    int d = dst[i];
    int slot = atomicAdd(&cur[d], 1);
    csr[off[d] + slot] = src[i];
  }
}

// ---------------- W transpose -> bf16 Wt[c][k], both layers in one launch ----------------
__global__ void twt_kernel(const float* __restrict__ W0, const float* __restrict__ W1,
                           unsigned short* __restrict__ Wt0, unsigned short* __restrict__ Wt1){
  int t = blockIdx.x*256 + threadIdx.x;   // 0..32767
  int which = t >> 14;
  int i = t & 16383;
  int c = i >> 7, k = i & 127;
  const float* W = which ? W1 : W0;
  unsigned short* Wt = which ? Wt1 : Wt0;
  Wt[i] = f2bf(W[k*128 + c]);
}

// ---------------- GEMM: Z(bf16) = A @ W, fused el/er epilogue ----------------
// BM=64 tile (LDS 48KB). Wave w holds rows w*16+(lane>>4)*4+r, cols n*16+(lane&15);
// head h == col-block n, so el/er reduce is a 16-lane xor-shuffle.
__global__ __launch_bounds__(256) void gemm_nt(
    const float* __restrict__ A, const int* __restrict__ gidx,
    const unsigned short* __restrict__ Wt,   // bf16 [col][k]
    const float* __restrict__ al, const float* __restrict__ ar,
    unsigned short* __restrict__ Z,          // bf16 [N][128]
    float* __restrict__ elp, float* __restrict__ erp)
{
  __shared__ unsigned short As[64*128];      // 16KB
  __shared__ unsigned short Bs[128*128];     // 32KB
  int t = threadIdx.x;
  int brow = blockIdx.x * 64;
  {
    int r = t >> 2, q = t & 3;               // 4 threads per row, 32 cols each
    int grow = brow + r;
    bool valid = grow < N_NODES;
    unsigned srcr = valid ? (gidx ? (unsigned)gidx[grow] : (unsigned)grow) : 0u;
    const float* arow = A + (size_t)srcr * DIM;
    #pragma unroll
    for (int j = 0; j < 4; ++j){
      int c = q*32 + j*8;
      float4 a0, a1;
      if (valid){ a0 = *(const float4*)(arow + c); a1 = *(const float4*)(arow + c + 4); }
      else { a0 = make_float4(0.f,0.f,0.f,0.f); a1 = a0; }
      short8v pk;
      pk[0]=(short)f2bf(a0.x); pk[1]=(short)f2bf(a0.y); pk[2]=(short)f2bf(a0.z); pk[3]=(short)f2bf(a0.w);
      pk[4]=(short)f2bf(a1.x); pk[5]=(short)f2bf(a1.y); pk[6]=(short)f2bf(a1.z); pk[7]=(short)f2bf(a1.w);
      int byte = (r*256 + c*2) ^ ((r & 7) << 4);
      *(short8v*)((char*)As + byte) = pk;
    }
    int cc = t >> 1, khalf = t & 1;
    #pragma unroll
    for (int j = 0; j < 8; ++j){
      int k0 = khalf*64 + j*8;
      short8v w = *(const short8v*)(Wt + cc*128 + k0);
      int byte = (cc*256 + k0*2) ^ ((cc & 7) << 4);
      *(short8v*)((char*)Bs + byte) = w;
    }
  }
  __syncthreads();
  int w = t >> 6, lane = t & 63;
  f32x4 acc[8];
  #pragma unroll
  for (int n=0;n<8;n++) acc[n] = (f32x4){0.f,0.f,0.f,0.f};
  #pragma unroll
  for (int kk = 0; kk < 4; ++kk){
    int ks = kk*32 + (lane>>4)*8;
    int row = w*16 + (lane & 15);
    int abyte = (row*256 + ks*2) ^ ((row & 7) << 4);
    short8v a = *(const short8v*)((const char*)As + abyte);
    short8v b[8];
    #pragma unroll
    for (int n=0;n<8;n++){
      int col = n*16 + (lane & 15);
      int byte = (col*256 + ks*2) ^ ((col & 7) << 4);
      b[n] = *(const short8v*)((const char*)Bs + byte);
    }
    #pragma unroll
    for (int n=0;n<8;n++)
      acc[n] = __builtin_amdgcn_mfma_f32_16x16x32_bf16(a, b[n], acc[n], 0, 0, 0);
  }
  int row_base = brow + w*16 + ((lane>>4)<<2);
  int o = lane & 15;
  #pragma unroll
  for (int r=0;r<4;r++){
    int grow = row_base + r;
    if (grow < N_NODES){
      #pragma unroll
      for (int n=0;n<8;n++)
        Z[(unsigned)grow*128u + n*16 + o] = f2bf(acc[n][r]);
    }
  }
  // fused el/er
  #pragma unroll
  for (int n=0;n<8;n++){
    float a_l = al[n*16 + o];
    float a_r = ar[n*16 + o];
    #pragma unroll
    for (int r=0;r<4;r++){
      float sl = acc[n][r] * a_l;
      float sr = acc[n][r] * a_r;
      #pragma unroll
      for (int m=1;m<16;m<<=1){
        sl += __shfl_xor(sl, m, 64);
        sr += __shfl_xor(sr, m, 64);
      }
      int grow = row_base + r;
      if (o == n && grow < N_NODES){
        elp[(unsigned)grow*8u + n] = sl;
        erp[(unsigned)grow*8u + n] = sr;
      }
    }
  }
}

// ---------------- per-node attention aggregate + residual + bias (+act) ----------------
// 1 wave per node; scalarized edge walk; masked 16-edge batches (32 gathers in flight).
__global__ __launch_bounds__(256) void edge_agg(
    const unsigned short* __restrict__ Z, const float* __restrict__ el,
    const float* __restrict__ er, const int* __restrict__ off,
    const int* __restrict__ csr, const float* __restrict__ Hin,
    const int* __restrict__ gidx, const float* __restrict__ bias,
    float* __restrict__ Hout, int activate)
{
  int tid  = threadIdx.x;
  int lane = tid & 63;
  int n    = __builtin_amdgcn_readfirstlane((int)(blockIdx.x*4 + (tid >> 6)));
  if (n >= N_NODES) return;
  int head = lane >> 3;

  int lo = off[n], hi = off[n+1];
  float ern = er[(unsigned)n*8u + head];
  float acc0a=0.f, acc0b=0.f, acc1a=0.f, acc1b=0.f, sacca=0.f, saccb=0.f;
  const unsigned lidx = (unsigned)(lane*2);          // ushort index within Z row

  for (int base = lo; base < hi; base += 16){
    int s[16]; float x[16]; unsigned zz[16]; float wv[16];
    #pragma unroll
    for (int j=0;j<16;++j){
      int idx = base + j;
      s[j] = csr[idx < hi ? idx : hi-1];
    }
    #pragma unroll
    for (int j=0;j<16;++j) x[j] = el[(unsigned)s[j]*8u + head] + ern;
    #pragma unroll
    for (int j=0;j<16;++j) zz[j] = *(const unsigned*)(Z + (unsigned)s[j]*128u + lidx);
    #pragma unroll
    for (int j=0;j<16;++j){
      float xv = fmaxf(x[j], 0.2f*x[j]);             // leaky_relu 0.2
      wv[j] = (base + j < hi) ? __expf(xv) : 0.f;    // masked (no max-shift: |e|<<1)
    }
    #pragma unroll
    for (int j=0;j<16;j+=2){
      sacca += wv[j];           saccb += wv[j+1];
      acc0a += wv[j]*lo16f(zz[j]);   acc0b += wv[j+1]*lo16f(zz[j+1]);
      acc1a += wv[j]*hi16f(zz[j]);   acc1b += wv[j+1]*hi16f(zz[j+1]);
    }
  }
  float sacc = sacca + saccb;
  float acc0 = acc0a + acc0b;
  float acc1 = acc1a + acc1b;
  float inv = (hi > lo) ? (1.f / sacc) : 0.f;
  unsigned hrow = gidx ? (unsigned)gidx[n] : (unsigned)n;
  int d = lane*2;
  float h0 = Hin[hrow*128u + d], h1v = Hin[hrow*128u + d + 1];
  float r0 = acc0*inv + h0 + bias[d];
  float r1 = acc1*inv + h1v + bias[d+1];
  if (activate){
    r0 = (r0 > 0.f) ? r0 : 0.01f*r0;
    r1 = (r1 > 0.f) ? r1 : 0.01f*r1;
  }
  Hout[(unsigned)n*128u + d]     = r0;
  Hout[(unsigned)n*128u + d + 1] = r1;
}

// ---------------- L2 normalize + gather out = v[x] ----------------
__global__ __launch_bounds__(256) void norm_gather(const float* __restrict__ H,
    const int* __restrict__ x, float* __restrict__ out)
{
  int row = blockIdx.x*4 + (threadIdx.x >> 6);
  if (row >= BT) return;
  int lane = threadIdx.x & 63;
  unsigned xi = (unsigned)x[row];
  int d = lane*2;
  float v0 = H[xi*128u + d], v1 = H[xi*128u + d + 1];
  float ss = v0*v0 + v1*v1;
  #pragma unroll
  for (int m = 32; m; m >>= 1) ss += __shfl_xor(ss, m, 64);
  float sc = 1.f / fmaxf(sqrtf(ss), 1e-5f);
  out[(size_t)row*128 + d]     = v0*sc;
  out[(size_t)row*128 + d + 1] = v1*sc;
}

extern "C" void kernel_launch(void* const* d_in, const int* in_sizes, int n_in,
                              void* d_out, int out_size, void* d_ws, size_t ws_size,
                              hipStream_t stream)
{
  const float* emb = (const float*)d_in[0];
  const float* W0  = (const float*)d_in[1];
  const float* al0 = (const float*)d_in[2];
  const float* ar0 = (const float*)d_in[3];
  const float* b0  = (const float*)d_in[4];
  const float* W1  = (const float*)d_in[5];
  const float* al1 = (const float*)d_in[6];
  const float* ar1 = (const float*)d_in[7];
  const float* b1  = (const float*)d_in[8];
  const int* n_feat = (const int*)d_in[9];
  const int* srcv = (const int*)d_in[10];
  const int* dstv = (const int*)d_in[11];
  const int* xv   = (const int*)d_in[12];
  float* out = (float*)d_out;

  char* p = (char*)d_ws;
  auto alloc = [&](size_t b)->char*{ char* q = p; p += (b + 255) & ~(size_t)255; return q; };
  unsigned short* Z   = (unsigned short*)alloc((size_t)N_NODES*128*2);
  float* H1  = (float*)alloc((size_t)N_NODES*128*4);
  float* H2  = (float*)alloc((size_t)N_NODES*128*4);
  float* el  = (float*)alloc((size_t)N_NODES*8*4);
  float* er  = (float*)alloc((size_t)N_NODES*8*4);
  int* deg   = (int*)alloc((size_t)N_NODES*4);
  int* cur   = (int*)alloc((size_t)N_NODES*4);
  int* offs  = (int*)alloc((size_t)(N_NODES+1)*4);
  int* csr   = (int*)alloc((size_t)N_EDGES*4);
  int* bsum  = (int*)alloc(256*4);
  int* bbase = (int*)alloc(256*4);
  unsigned short* Wt0 = (unsigned short*)alloc(128*128*2);
  unsigned short* Wt1 = (unsigned short*)alloc(128*128*2);

  hipMemsetAsync(deg, 0, (size_t)N_NODES*4, stream);
  hipMemsetAsync(cur, 0, (size_t)N_NODES*4, stream);

  int nb_scan = (N_NODES + 255)/256;                 // 224 (<=256 required)
  int egrid   = (N_EDGES + 255)/256;

  hist_kernel<<<egrid, 256, 0, stream>>>(dstv, deg);
  scan_partial<<<nb_scan, 256, 0, stream>>>(deg, offs, bsum);
  scan_top<<<1, 256, 0, stream>>>(bsum, bbase, offs, nb_scan);
  scan_add<<<nb_scan, 256, 0, stream>>>(offs, bbase);
  scatter_kernel<<<egrid, 256, 0, stream>>>(srcv, dstv, offs, cur, csr);

  twt_kernel<<<128, 256, 0, stream>>>(W0, W1, Wt0, Wt1);

  int gemm_grid = (N_NODES + 63)/64;
  int agg_grid  = (N_NODES + 3)/4;

  // layer 0 (input rows gathered emb[n_feat], activation on)
  gemm_nt<<<gemm_grid, 256, 0, stream>>>(emb, n_feat, Wt0, al0, ar0, Z, el, er);
  edge_agg<<<agg_grid, 256, 0, stream>>>(Z, el, er, offs, csr, emb, n_feat, b0, H1, 1);
  // layer 1 (no activation)
  gemm_nt<<<gemm_grid, 256, 0, stream>>>(H1, nullptr, Wt1, al1, ar1, Z, el, er);
  edge_agg<<<agg_grid, 256, 0, stream>>>(Z, el, er, offs, csr, H1, nullptr, b1, H2, 0);
  // normalize + output gather
  norm_gather<<<(BT + 3)/4, 256, 0, stream>>>(H2, xv, out);
}

// Round 5
// 213.290 us; speedup vs baseline: 1.7223x; 1.3113x over previous
//
#include <hip/hip_runtime.h>

#define N_NODES 57254
#define N_EDGES 916064
#define DIM 128
#define NHEAD 8
#define BT (64*512)
#define NBKT 224                 // dst>>8 buckets (57254>>8 == 223)
#define NCHUNK 256
#define CHUNK 3579               // ceil(916064/256)

typedef __attribute__((ext_vector_type(8))) short short8v;
typedef __attribute__((ext_vector_type(4))) float f32x4;

static __device__ __forceinline__ unsigned short f2bf(float f){
  unsigned int b = __builtin_bit_cast(unsigned int, f);
  b += 0x7fffu + ((b >> 16) & 1u);           // round-to-nearest-even
  return (unsigned short)(b >> 16);
}
static __device__ __forceinline__ float lo16f(unsigned int zz){
  return __builtin_bit_cast(float, zz << 16);
}
static __device__ __forceinline__ float hi16f(unsigned int zz){
  return __builtin_bit_cast(float, zz & 0xffff0000u);
}

// ---------------- CSR build: two-level counting sort, no global atomics ----------------

// Phase 1a: per-chunk histogram of coarse buckets (dst>>8).
__global__ __launch_bounds__(256) void p1hist(const int* __restrict__ dst,
                                              int* __restrict__ bh){
  __shared__ int h[NBKT];
  int t = threadIdx.x, c = blockIdx.x;
  if (t < NBKT) h[t] = 0;
  __syncthreads();
  int lo = c*CHUNK, hi = lo + CHUNK; if (hi > N_EDGES) hi = N_EDGES;
  for (int i = lo + t; i < hi; i += 256)
    atomicAdd(&h[((unsigned)dst[i]) >> 8], 1);
  __syncthreads();
  if (t < NBKT) bh[t*NCHUNK + c] = h[t];     // bucket-major layout for scan
}

// generic block scan over n (multiple of 256) elements
__global__ void scan_partial(const int* __restrict__ in, int* __restrict__ out,
                             int* __restrict__ bsum, int n){
  __shared__ int sm[256];
  int tid = threadIdx.x;
  int i = blockIdx.x*256 + tid;
  int v = (i < n) ? in[i] : 0;
  sm[tid] = v;
  __syncthreads();
  #pragma unroll
  for (int d = 1; d < 256; d <<= 1){
    int add = (tid >= d) ? sm[tid - d] : 0;
    __syncthreads();
    sm[tid] += add;
    __syncthreads();
  }
  if (i < n) out[i] = sm[tid] - v;
  if (tid == 255) bsum[blockIdx.x] = sm[255];
}

__global__ void scan_top(const int* __restrict__ bsum, int* __restrict__ bbase, int nb){
  __shared__ int sm[256];
  int tid = threadIdx.x;
  int v = (tid < nb) ? bsum[tid] : 0;
  sm[tid] = v;
  __syncthreads();
  #pragma unroll
  for (int d = 1; d < 256; d <<= 1){
    int add = (tid >= d) ? sm[tid - d] : 0;
    __syncthreads();
    sm[tid] += add;
    __syncthreads();
  }
  if (tid < nb) bbase[tid] = sm[tid] - v;
}

__global__ void scan_add(int* __restrict__ out, const int* __restrict__ bbase, int n){
  int i = blockIdx.x*256 + threadIdx.x;
  if (i < n) out[i] += bbase[blockIdx.x];
}

// Phase 1b: LDS-staged coarse scatter. Edge packed as (src<<16)|(dst&255).
__global__ __launch_bounds__(256) void p1scat(const int* __restrict__ src,
                                              const int* __restrict__ dst,
                                              const int* __restrict__ bases,
                                              unsigned* __restrict__ ebuf){
  __shared__ unsigned stage[CHUNK];
  __shared__ int lh[256], sm[256], ls[256], cur[NBKT], gb[NBKT];
  int t = threadIdx.x, c = blockIdx.x;
  lh[t] = 0;
  __syncthreads();
  int lo = c*CHUNK, hi = lo + CHUNK; if (hi > N_EDGES) hi = N_EDGES;
  int len = hi - lo;
  for (int i = lo + t; i < hi; i += 256)
    atomicAdd(&lh[((unsigned)dst[i]) >> 8], 1);
  __syncthreads();
  int v = lh[t];
  sm[t] = v;
  __syncthreads();
  #pragma unroll
  for (int d = 1; d < 256; d <<= 1){
    int add = (t >= d) ? sm[t - d] : 0;
    __syncthreads();
    sm[t] += add;
    __syncthreads();
  }
  ls[t] = sm[t] - v;                          // exclusive; ls[NBKT]==len implied
  if (t < NBKT){ gb[t] = bases[t*NCHUNK + c]; cur[t] = sm[t] - v; }
  __syncthreads();
  for (int i = lo + t; i < hi; i += 256){
    unsigned d = (unsigned)dst[i];
    int b = d >> 8;
    int pos = atomicAdd(&cur[b], 1);
    stage[pos] = (((unsigned)src[i]) << 16) | (d & 255u);
  }
  __syncthreads();
  for (int k = t; k < len; k += 256){
    int lo_ = 0, hi_ = NBKT;                  // find bucket: ls[b] <= k < next
    while (hi_ - lo_ > 1){
      int mid = (lo_ + hi_) >> 1;
      int lsm = (mid < NBKT) ? ls[mid] : len;
      if (lsm <= k) lo_ = mid; else hi_ = mid;
    }
    ebuf[gb[lo_] + (k - ls[lo_])] = stage[k];
  }
}

// Phase 2: per-bucket fine sort -> offs + csr (writes confined to private 16KB window)
__global__ __launch_bounds__(256) void p2fine(const unsigned* __restrict__ ebuf,
                                              const int* __restrict__ bases,
                                              int* __restrict__ offs,
                                              int* __restrict__ csr){
  __shared__ int cnt[256], sm[256], loff[256], cur[256];
  int t = threadIdx.x, b = blockIdx.x;
  int bstart = bases[b*NCHUNK];
  int bend   = (b < NBKT-1) ? bases[(b+1)*NCHUNK] : N_EDGES;
  cnt[t] = 0;
  __syncthreads();
  for (int i = bstart + t; i < bend; i += 256)
    atomicAdd(&cnt[ebuf[i] & 255u], 1);
  __syncthreads();
  int v = cnt[t];
  sm[t] = v;
  __syncthreads();
  #pragma unroll
  for (int d = 1; d < 256; d <<= 1){
    int add = (t >= d) ? sm[t - d] : 0;
    __syncthreads();
    sm[t] += add;
    __syncthreads();
  }
  loff[t] = sm[t] - v;
  cur[t]  = bstart + sm[t] - v;
  int nlo = b*256;
  int nn  = N_NODES - nlo; if (nn > 256) nn = 256;
  if (t < nn) offs[nlo + t] = bstart + loff[t];
  if (b == NBKT-1 && t == 0) offs[N_NODES] = N_EDGES;
  __syncthreads();
  for (int i = bstart + t; i < bend; i += 256){
    unsigned e = ebuf[i];
    int pos = atomicAdd(&cur[e & 255u], 1);
    csr[pos] = (int)(e >> 16);
  }
}

// ---------------- W transpose -> bf16 Wt[c][k], both layers in one launch ----------------
__global__ void twt_kernel(const float* __restrict__ W0, const float* __restrict__ W1,
                           unsigned short* __restrict__ Wt0, unsigned short* __restrict__ Wt1){
  int t = blockIdx.x*256 + threadIdx.x;   // 0..32767
  int which = t >> 14;
  int i = t & 16383;
  int c = i >> 7, k = i & 127;
  const float* W = which ? W1 : W0;
  unsigned short* Wt = which ? Wt1 : Wt0;
  Wt[i] = f2bf(W[k*128 + c]);
}

// ---------------- GEMM: Z(bf16) = A @ W, fused el/er epilogue ----------------
__global__ __launch_bounds__(256) void gemm_nt(
    const float* __restrict__ A, const int* __restrict__ gidx,
    const unsigned short* __restrict__ Wt,   // bf16 [col][k]
    const float* __restrict__ al, const float* __restrict__ ar,
    unsigned short* __restrict__ Z,          // bf16 [N][128]
    float* __restrict__ elp, float* __restrict__ erp)
{
  __shared__ unsigned short As[64*128];      // 16KB
  __shared__ unsigned short Bs[128*128];     // 32KB
  int t = threadIdx.x;
  int brow = blockIdx.x * 64;
  {
    int r = t >> 2, q = t & 3;               // 4 threads per row, 32 cols each
    int grow = brow + r;
    bool valid = grow < N_NODES;
    unsigned srcr = valid ? (gidx ? (unsigned)gidx[grow] : (unsigned)grow) : 0u;
    const float* arow = A + (size_t)srcr * DIM;
    #pragma unroll
    for (int j = 0; j < 4; ++j){
      int c = q*32 + j*8;
      float4 a0, a1;
      if (valid){ a0 = *(const float4*)(arow + c); a1 = *(const float4*)(arow + c + 4); }
      else { a0 = make_float4(0.f,0.f,0.f,0.f); a1 = a0; }
      short8v pk;
      pk[0]=(short)f2bf(a0.x); pk[1]=(short)f2bf(a0.y); pk[2]=(short)f2bf(a0.z); pk[3]=(short)f2bf(a0.w);
      pk[4]=(short)f2bf(a1.x); pk[5]=(short)f2bf(a1.y); pk[6]=(short)f2bf(a1.z); pk[7]=(short)f2bf(a1.w);
      int byte = (r*256 + c*2) ^ ((r & 7) << 4);
      *(short8v*)((char*)As + byte) = pk;
    }
    int cc = t >> 1, khalf = t & 1;
    #pragma unroll
    for (int j = 0; j < 8; ++j){
      int k0 = khalf*64 + j*8;
      short8v w = *(const short8v*)(Wt + cc*128 + k0);
      int byte = (cc*256 + k0*2) ^ ((cc & 7) << 4);
      *(short8v*)((char*)Bs + byte) = w;
    }
  }
  __syncthreads();
  int w = t >> 6, lane = t & 63;
  f32x4 acc[8];
  #pragma unroll
  for (int n=0;n<8;n++) acc[n] = (f32x4){0.f,0.f,0.f,0.f};
  #pragma unroll
  for (int kk = 0; kk < 4; ++kk){
    int ks = kk*32 + (lane>>4)*8;
    int row = w*16 + (lane & 15);
    int abyte = (row*256 + ks*2) ^ ((row & 7) << 4);
    short8v a = *(const short8v*)((const char*)As + abyte);
    short8v b[8];
    #pragma unroll
    for (int n=0;n<8;n++){
      int col = n*16 + (lane & 15);
      int byte = (col*256 + ks*2) ^ ((col & 7) << 4);
      b[n] = *(const short8v*)((const char*)Bs + byte);
    }
    #pragma unroll
    for (int n=0;n<8;n++)
      acc[n] = __builtin_amdgcn_mfma_f32_16x16x32_bf16(a, b[n], acc[n], 0, 0, 0);
  }
  int row_base = brow + w*16 + ((lane>>4)<<2);
  int o = lane & 15;
  #pragma unroll
  for (int r=0;r<4;r++){
    int grow = row_base + r;
    if (grow < N_NODES){
      #pragma unroll
      for (int n=0;n<8;n++)
        Z[(unsigned)grow*128u + n*16 + o] = f2bf(acc[n][r]);
    }
  }
  // fused el/er
  #pragma unroll
  for (int n=0;n<8;n++){
    float a_l = al[n*16 + o];
    float a_r = ar[n*16 + o];
    #pragma unroll
    for (int r=0;r<4;r++){
      float sl = acc[n][r] * a_l;
      float sr = acc[n][r] * a_r;
      #pragma unroll
      for (int m=1;m<16;m<<=1){
        sl += __shfl_xor(sl, m, 64);
        sr += __shfl_xor(sr, m, 64);
      }
      int grow = row_base + r;
      if (o == n && grow < N_NODES){
        elp[(unsigned)grow*8u + n] = sl;
        erp[(unsigned)grow*8u + n] = sr;
      }
    }
  }
}

// ---------------- per-node attention aggregate + residual + bias (+act) ----------------
__global__ __launch_bounds__(256) void edge_agg(
    const unsigned short* __restrict__ Z, const float* __restrict__ el,
    const float* __restrict__ er, const int* __restrict__ off,
    const int* __restrict__ csr, const float* __restrict__ Hin,
    const int* __restrict__ gidx, const float* __restrict__ bias,
    float* __restrict__ Hout, int activate)
{
  int tid  = threadIdx.x;
  int lane = tid & 63;
  int n    = __builtin_amdgcn_readfirstlane((int)(blockIdx.x*4 + (tid >> 6)));
  if (n >= N_NODES) return;
  int head = lane >> 3;

  int lo = off[n], hi = off[n+1];
  float ern = er[(unsigned)n*8u + head];
  float acc0a=0.f, acc0b=0.f, acc1a=0.f, acc1b=0.f, sacca=0.f, saccb=0.f;
  const unsigned lidx = (unsigned)(lane*2);          // ushort index within Z row

  for (int base = lo; base < hi; base += 16){
    int s[16]; float x[16]; unsigned zz[16]; float wv[16];
    #pragma unroll
    for (int j=0;j<16;++j){
      int idx = base + j;
      s[j] = csr[idx < hi ? idx : hi-1];
    }
    #pragma unroll
    for (int j=0;j<16;++j) x[j] = el[(unsigned)s[j]*8u + head] + ern;
    #pragma unroll
    for (int j=0;j<16;++j) zz[j] = *(const unsigned*)(Z + (unsigned)s[j]*128u + lidx);
    #pragma unroll
    for (int j=0;j<16;++j){
      float xv = fmaxf(x[j], 0.2f*x[j]);             // leaky_relu 0.2
      wv[j] = (base + j < hi) ? __expf(xv) : 0.f;    // masked (no max-shift: |e|<<1)
    }
    #pragma unroll
    for (int j=0;j<16;j+=2){
      sacca += wv[j];           saccb += wv[j+1];
      acc0a += wv[j]*lo16f(zz[j]);   acc0b += wv[j+1]*lo16f(zz[j+1]);
      acc1a += wv[j]*hi16f(zz[j]);   acc1b += wv[j+1]*hi16f(zz[j+1]);
    }
  }
  float sacc = sacca + saccb;
  float acc0 = acc0a + acc0b;
  float acc1 = acc1a + acc1b;
  float inv = (hi > lo) ? (1.f / sacc) : 0.f;
  unsigned hrow = gidx ? (unsigned)gidx[n] : (unsigned)n;
  int d = lane*2;
  float h0 = Hin[hrow*128u + d], h1v = Hin[hrow*128u + d + 1];
  float r0 = acc0*inv + h0 + bias[d];
  float r1 = acc1*inv + h1v + bias[d+1];
  if (activate){
    r0 = (r0 > 0.f) ? r0 : 0.01f*r0;
    r1 = (r1 > 0.f) ? r1 : 0.01f*r1;
  }
  Hout[(unsigned)n*128u + d]     = r0;
  Hout[(unsigned)n*128u + d + 1] = r1;
}

// ---------------- L2 normalize + gather out = v[x] ----------------
__global__ __launch_bounds__(256) void norm_gather(const float* __restrict__ H,
    const int* __restrict__ x, float* __restrict__ out)
{
  int row = blockIdx.x*4 + (threadIdx.x >> 6);
  if (row >= BT) return;
  int lane = threadIdx.x & 63;
  unsigned xi = (unsigned)x[row];
  int d = lane*2;
  float v0 = H[xi*128u + d], v1 = H[xi*128u + d + 1];
  float ss = v0*v0 + v1*v1;
  #pragma unroll
  for (int m = 32; m; m >>= 1) ss += __shfl_xor(ss, m, 64);
  float sc = 1.f / fmaxf(sqrtf(ss), 1e-5f);
  out[(size_t)row*128 + d]     = v0*sc;
  out[(size_t)row*128 + d + 1] = v1*sc;
}

extern "C" void kernel_launch(void* const* d_in, const int* in_sizes, int n_in,
                              void* d_out, int out_size, void* d_ws, size_t ws_size,
                              hipStream_t stream)
{
  const float* emb = (const float*)d_in[0];
  const float* W0  = (const float*)d_in[1];
  const float* al0 = (const float*)d_in[2];
  const float* ar0 = (const float*)d_in[3];
  const float* b0  = (const float*)d_in[4];
  const float* W1  = (const float*)d_in[5];
  const float* al1 = (const float*)d_in[6];
  const float* ar1 = (const float*)d_in[7];
  const float* b1  = (const float*)d_in[8];
  const int* n_feat = (const int*)d_in[9];
  const int* srcv = (const int*)d_in[10];
  const int* dstv = (const int*)d_in[11];
  const int* xv   = (const int*)d_in[12];
  float* out = (float*)d_out;

  char* p = (char*)d_ws;
  auto alloc = [&](size_t b)->char*{ char* q = p; p += (b + 255) & ~(size_t)255; return q; };
  unsigned short* Z   = (unsigned short*)alloc((size_t)N_NODES*128*2);
  float* H1  = (float*)alloc((size_t)N_NODES*128*4);     // also layer-1 output (in-place residual)
  int* offs  = (int*)alloc((size_t)(N_NODES+1)*4);
  int* csr   = (int*)alloc((size_t)N_EDGES*4);
  unsigned* ebuf = (unsigned*)alloc((size_t)N_EDGES*4);  // dead after p2fine; reused for el/er
  int* bh    = (int*)alloc((size_t)NBKT*NCHUNK*4);
  int* bsum  = (int*)alloc(256*4);
  int* bbase = (int*)alloc(256*4);
  unsigned short* Wt0 = (unsigned short*)alloc(128*128*2);
  unsigned short* Wt1 = (unsigned short*)alloc(128*128*2);
  float* el = (float*)ebuf;                              // N*8 floats
  float* er = el + (size_t)N_NODES*8;                    // N*8 floats (fits: 2*N*8*4 == E*4)

  const int NSCAN = NBKT*NCHUNK;                         // 57344

  // CSR build (no global atomics)
  p1hist<<<NCHUNK, 256, 0, stream>>>(dstv, bh);
  scan_partial<<<NSCAN/256, 256, 0, stream>>>(bh, bh, bsum, NSCAN);
  scan_top<<<1, 256, 0, stream>>>(bsum, bbase, NSCAN/256);
  scan_add<<<NSCAN/256, 256, 0, stream>>>(bh, bbase, NSCAN);
  p1scat<<<NCHUNK, 256, 0, stream>>>(srcv, dstv, bh, ebuf);
  p2fine<<<NBKT, 256, 0, stream>>>(ebuf, bh, offs, csr);

  twt_kernel<<<128, 256, 0, stream>>>(W0, W1, Wt0, Wt1);

  int gemm_grid = (N_NODES + 63)/64;
  int agg_grid  = (N_NODES + 3)/4;

  // layer 0 (input rows gathered emb[n_feat], activation on)
  gemm_nt<<<gemm_grid, 256, 0, stream>>>(emb, n_feat, Wt0, al0, ar0, Z, el, er);
  edge_agg<<<agg_grid, 256, 0, stream>>>(Z, el, er, offs, csr, emb, n_feat, b0, H1, 1);
  // layer 1 (no activation; residual in-place safe: wave reads row n before writing it)
  gemm_nt<<<gemm_grid, 256, 0, stream>>>(H1, nullptr, Wt1, al1, ar1, Z, el, er);
  edge_agg<<<agg_grid, 256, 0, stream>>>(Z, el, er, offs, csr, H1, nullptr, b1, H1, 0);
  // normalize + output gather
  norm_gather<<<(BT + 3)/4, 256, 0, stream>>>(H1, xv, out);
}

// Round 6
// 204.806 us; speedup vs baseline: 1.7936x; 1.0414x over previous
//
#include <hip/hip_runtime.h>

#define N_NODES 57254
#define N_EDGES 916064
#define DIM 128
#define NHEAD 8
#define BT (64*512)
#define NBKT 224                 // dst>>8 buckets (57254>>8 == 223)
#define NCHUNK 256
#define CHUNK 3579               // ceil(916064/256)

typedef __attribute__((ext_vector_type(8))) short short8v;
typedef __attribute__((ext_vector_type(4))) float f32x4;

static __device__ __forceinline__ unsigned short f2bf(float f){
  unsigned int b = __builtin_bit_cast(unsigned int, f);
  b += 0x7fffu + ((b >> 16) & 1u);           // round-to-nearest-even
  return (unsigned short)(b >> 16);
}
static __device__ __forceinline__ float lo16f(unsigned int zz){
  return __builtin_bit_cast(float, zz << 16);
}
static __device__ __forceinline__ float hi16f(unsigned int zz){
  return __builtin_bit_cast(float, zz & 0xffff0000u);
}

// ---------------- CSR build: two-level counting sort, no global atomics ----------------

__global__ __launch_bounds__(256) void p1hist(const int* __restrict__ dst,
                                              int* __restrict__ bh){
  __shared__ int h[NBKT];
  int t = threadIdx.x, c = blockIdx.x;
  if (t < NBKT) h[t] = 0;
  __syncthreads();
  int lo = c*CHUNK, hi = lo + CHUNK; if (hi > N_EDGES) hi = N_EDGES;
  for (int i = lo + t; i < hi; i += 256)
    atomicAdd(&h[((unsigned)dst[i]) >> 8], 1);
  __syncthreads();
  if (t < NBKT) bh[t*NCHUNK + c] = h[t];     // bucket-major layout for scan
}

__global__ void scan_partial(const int* __restrict__ in, int* __restrict__ out,
                             int* __restrict__ bsum, int n){
  __shared__ int sm[256];
  int tid = threadIdx.x;
  int i = blockIdx.x*256 + tid;
  int v = (i < n) ? in[i] : 0;
  sm[tid] = v;
  __syncthreads();
  #pragma unroll
  for (int d = 1; d < 256; d <<= 1){
    int add = (tid >= d) ? sm[tid - d] : 0;
    __syncthreads();
    sm[tid] += add;
    __syncthreads();
  }
  if (i < n) out[i] = sm[tid] - v;
  if (tid == 255) bsum[blockIdx.x] = sm[255];
}

// block b adds sum(bsum[0..b)) to its 256 elements (replaces scan_top+scan_add)
__global__ void scan_add2(int* __restrict__ out, const int* __restrict__ bsum,
                          int nb, int n){
  __shared__ int sm[256];
  int t = threadIdx.x, b = blockIdx.x;
  sm[t] = (t < b && t < nb) ? bsum[t] : 0;
  __syncthreads();
  #pragma unroll
  for (int d = 128; d; d >>= 1){
    if (t < d) sm[t] += sm[t + d];
    __syncthreads();
  }
  int i = b*256 + t;
  if (i < n) out[i] += sm[0];
}

// Phase 1b: LDS-staged coarse scatter. Edge packed as (src<<16)|(dst&255).
__global__ __launch_bounds__(256) void p1scat(const int* __restrict__ src,
                                              const int* __restrict__ dst,
                                              const int* __restrict__ bases,
                                              unsigned* __restrict__ ebuf){
  __shared__ unsigned stage[CHUNK];
  __shared__ short bkt_of[CHUNK];
  __shared__ int lh[256], smm[256], ls[NBKT+1], cur[NBKT], gb[NBKT];
  int t = threadIdx.x, c = blockIdx.x;
  lh[t] = 0;
  __syncthreads();
  int lo = c*CHUNK, hi = lo + CHUNK; if (hi > N_EDGES) hi = N_EDGES;
  int len = hi - lo;
  for (int i = lo + t; i < hi; i += 256)
    atomicAdd(&lh[((unsigned)dst[i]) >> 8], 1);
  __syncthreads();
  int v = lh[t];
  smm[t] = v;
  __syncthreads();
  #pragma unroll
  for (int d = 1; d < 256; d <<= 1){
    int add = (t >= d) ? smm[t - d] : 0;
    __syncthreads();
    smm[t] += add;
    __syncthreads();
  }
  if (t < NBKT){ ls[t] = smm[t] - v; cur[t] = smm[t] - v; gb[t] = bases[t*NCHUNK + c]; }
  if (t == 255) ls[NBKT] = smm[255];          // == len
  __syncthreads();
  if (t < NBKT){
    int e0 = ls[t], e1 = ls[t+1];
    for (int k = e0; k < e1; ++k) bkt_of[k] = (short)t;
  }
  __syncthreads();
  for (int i = lo + t; i < hi; i += 256){
    unsigned d = (unsigned)dst[i];
    int b = d >> 8;
    int pos = atomicAdd(&cur[b], 1);
    stage[pos] = (((unsigned)src[i]) << 16) | (d & 255u);
  }
  __syncthreads();
  for (int k = t; k < len; k += 256){
    int b = bkt_of[k];
    ebuf[gb[b] + (k - ls[b])] = stage[k];
  }
}

// Phase 2: per-bucket fine sort -> offs + csr (writes confined to private 16KB window)
__global__ __launch_bounds__(256) void p2fine(const unsigned* __restrict__ ebuf,
                                              const int* __restrict__ bases,
                                              int* __restrict__ offs,
                                              int* __restrict__ csr){
  __shared__ int cnt[256], sm[256], loff[256], cur[256];
  int t = threadIdx.x, b = blockIdx.x;
  int bstart = bases[b*NCHUNK];
  int bend   = (b < NBKT-1) ? bases[(b+1)*NCHUNK] : N_EDGES;
  cnt[t] = 0;
  __syncthreads();
  for (int i = bstart + t; i < bend; i += 256)
    atomicAdd(&cnt[ebuf[i] & 255u], 1);
  __syncthreads();
  int v = cnt[t];
  sm[t] = v;
  __syncthreads();
  #pragma unroll
  for (int d = 1; d < 256; d <<= 1){
    int add = (t >= d) ? sm[t - d] : 0;
    __syncthreads();
    sm[t] += add;
    __syncthreads();
  }
  loff[t] = sm[t] - v;
  cur[t]  = bstart + sm[t] - v;
  int nlo = b*256;
  int nn  = N_NODES - nlo; if (nn > 256) nn = 256;
  if (t < nn) offs[nlo + t] = bstart + loff[t];
  if (b == NBKT-1 && t == 0) offs[N_NODES] = N_EDGES;
  __syncthreads();
  for (int i = bstart + t; i < bend; i += 256){
    unsigned e = ebuf[i];
    int pos = atomicAdd(&cur[e & 255u], 1);
    csr[pos] = (int)(e >> 16);
  }
}

// ---------------- W transpose -> bf16 Wt[c][k], both layers in one launch ----------------
__global__ void twt_kernel(const float* __restrict__ W0, const float* __restrict__ W1,
                           unsigned short* __restrict__ Wt0, unsigned short* __restrict__ Wt1){
  int t = blockIdx.x*256 + threadIdx.x;   // 0..32767
  int which = t >> 14;
  int i = t & 16383;
  int c = i >> 7, k = i & 127;
  const float* W = which ? W1 : W0;
  unsigned short* Wt = which ? Wt1 : Wt0;
  Wt[i] = f2bf(W[k*128 + c]);
}

// ---------------- GEMM: Z(bf16) = A @ W, fused el/er epilogue ----------------
// MODE 0: A f32 + row-gather, also writes Hb (bf16 copy of gathered rows).
// MODE 1: A bf16 contiguous.
template<int MODE>
__global__ __launch_bounds__(256) void gemm_nt(
    const void* __restrict__ Av, const int* __restrict__ gidx,
    const unsigned short* __restrict__ Wt,   // bf16 [col][k]
    const float* __restrict__ al, const float* __restrict__ ar,
    unsigned short* __restrict__ Z,          // bf16 [N][128]
    float* __restrict__ elp, float* __restrict__ erp,
    unsigned short* __restrict__ Hb)
{
  __shared__ unsigned short As[64*128];      // 16KB
  __shared__ unsigned short Bs[128*128];     // 32KB
  int t = threadIdx.x;
  int brow = blockIdx.x * 64;
  {
    int r = t >> 2, q = t & 3;               // 4 threads per row, 32 cols each
    int grow = brow + r;
    bool valid = grow < N_NODES;
    #pragma unroll
    for (int j = 0; j < 4; ++j){
      int c = q*32 + j*8;
      short8v pk;
      if (MODE == 0){
        const float* A = (const float*)Av;
        unsigned srcr = valid ? (unsigned)gidx[grow] : 0u;
        const float* arow = A + (size_t)srcr * DIM;
        float4 a0, a1;
        if (valid){ a0 = *(const float4*)(arow + c); a1 = *(const float4*)(arow + c + 4); }
        else { a0 = make_float4(0.f,0.f,0.f,0.f); a1 = a0; }
        pk[0]=(short)f2bf(a0.x); pk[1]=(short)f2bf(a0.y); pk[2]=(short)f2bf(a0.z); pk[3]=(short)f2bf(a0.w);
        pk[4]=(short)f2bf(a1.x); pk[5]=(short)f2bf(a1.y); pk[6]=(short)f2bf(a1.z); pk[7]=(short)f2bf(a1.w);
        if (valid) *(short8v*)(Hb + (unsigned)grow*128u + c) = pk;
      } else {
        const unsigned short* A = (const unsigned short*)Av;
        if (valid) pk = *(const short8v*)(A + (unsigned)grow*128u + c);
        else       pk = (short8v){0,0,0,0,0,0,0,0};
      }
      int byte = (r*256 + c*2) ^ ((r & 7) << 4);
      *(short8v*)((char*)As + byte) = pk;
    }
    int cc = t >> 1, khalf = t & 1;
    #pragma unroll
    for (int j = 0; j < 8; ++j){
      int k0 = khalf*64 + j*8;
      short8v w = *(const short8v*)(Wt + cc*128 + k0);
      int byte = (cc*256 + k0*2) ^ ((cc & 7) << 4);
      *(short8v*)((char*)Bs + byte) = w;
    }
  }
  __syncthreads();
  int w = t >> 6, lane = t & 63;
  f32x4 acc[8];
  #pragma unroll
  for (int n=0;n<8;n++) acc[n] = (f32x4){0.f,0.f,0.f,0.f};
  #pragma unroll
  for (int kk = 0; kk < 4; ++kk){
    int ks = kk*32 + (lane>>4)*8;
    int row = w*16 + (lane & 15);
    int abyte = (row*256 + ks*2) ^ ((row & 7) << 4);
    short8v a = *(const short8v*)((const char*)As + abyte);
    short8v b[8];
    #pragma unroll
    for (int n=0;n<8;n++){
      int col = n*16 + (lane & 15);
      int byte = (col*256 + ks*2) ^ ((col & 7) << 4);
      b[n] = *(const short8v*)((const char*)Bs + byte);
    }
    #pragma unroll
    for (int n=0;n<8;n++)
      acc[n] = __builtin_amdgcn_mfma_f32_16x16x32_bf16(a, b[n], acc[n], 0, 0, 0);
  }
  int row_base = brow + w*16 + ((lane>>4)<<2);
  int o = lane & 15;
  #pragma unroll
  for (int r=0;r<4;r++){
    int grow = row_base + r;
    if (grow < N_NODES){
      #pragma unroll
      for (int n=0;n<8;n++)
        Z[(unsigned)grow*128u + n*16 + o] = f2bf(acc[n][r]);
    }
  }
  // fused el/er
  #pragma unroll
  for (int n=0;n<8;n++){
    float a_l = al[n*16 + o];
    float a_r = ar[n*16 + o];
    #pragma unroll
    for (int r=0;r<4;r++){
      float sl = acc[n][r] * a_l;
      float sr = acc[n][r] * a_r;
      #pragma unroll
      for (int m=1;m<16;m<<=1){
        sl += __shfl_xor(sl, m, 64);
        sr += __shfl_xor(sr, m, 64);
      }
      int grow = row_base + r;
      if (o == n && grow < N_NODES){
        elp[(unsigned)grow*8u + n] = sl;
        erp[(unsigned)grow*8u + n] = sr;
      }
    }
  }
}

// ---------------- per-node attention aggregate + residual + bias (+act) ----------------
// 1 wave per node; scalarized edge walk; masked 16-edge batches; bf16 H in/out.
__global__ __launch_bounds__(256) void edge_agg(
    const unsigned short* __restrict__ Z, const float* __restrict__ el,
    const float* __restrict__ er, const int* __restrict__ off,
    const int* __restrict__ csr, const unsigned short* __restrict__ Hin,
    const float* __restrict__ bias, unsigned short* __restrict__ Hout,
    int activate)
{
  int tid  = threadIdx.x;
  int lane = tid & 63;
  int n    = __builtin_amdgcn_readfirstlane((int)(blockIdx.x*4 + (tid >> 6)));
  if (n >= N_NODES) return;
  int head = lane >> 3;

  int lo = off[n], hi = off[n+1];
  float ern = er[(unsigned)n*8u + head];
  float acc0a=0.f, acc0b=0.f, acc1a=0.f, acc1b=0.f, sacca=0.f, saccb=0.f;
  const unsigned lidx = (unsigned)(lane*2);          // ushort index within row

  for (int base = lo; base < hi; base += 16){
    int s[16]; float x[16]; unsigned zz[16]; float wv[16];
    #pragma unroll
    for (int j=0;j<16;++j){
      int idx = base + j;
      s[j] = csr[idx < hi ? idx : hi-1];
    }
    #pragma unroll
    for (int j=0;j<16;++j) x[j] = el[(unsigned)s[j]*8u + head] + ern;
    #pragma unroll
    for (int j=0;j<16;++j) zz[j] = *(const unsigned*)(Z + (unsigned)s[j]*128u + lidx);
    #pragma unroll
    for (int j=0;j<16;++j){
      float xv = fmaxf(x[j], 0.2f*x[j]);             // leaky_relu 0.2
      wv[j] = (base + j < hi) ? __expf(xv) : 0.f;    // masked (no max-shift: |e|<<1)
    }
    #pragma unroll
    for (int j=0;j<16;j+=2){
      sacca += wv[j];           saccb += wv[j+1];
      acc0a += wv[j]*lo16f(zz[j]);   acc0b += wv[j+1]*lo16f(zz[j+1]);
      acc1a += wv[j]*hi16f(zz[j]);   acc1b += wv[j+1]*hi16f(zz[j+1]);
    }
  }
  float sacc = sacca + saccb;
  float acc0 = acc0a + acc0b;
  float acc1 = acc1a + acc1b;
  float inv = (hi > lo) ? (1.f / sacc) : 0.f;
  unsigned hv = *(const unsigned*)(Hin + (unsigned)n*128u + lidx);
  int d = lane*2;
  float r0 = acc0*inv + lo16f(hv) + bias[d];
  float r1 = acc1*inv + hi16f(hv) + bias[d+1];
  if (activate){
    r0 = (r0 > 0.f) ? r0 : 0.01f*r0;
    r1 = (r1 > 0.f) ? r1 : 0.01f*r1;
  }
  unsigned outv = ((unsigned)f2bf(r1) << 16) | (unsigned)f2bf(r0);
  *(unsigned*)(Hout + (unsigned)n*128u + lidx) = outv;
}

// ---------------- L2 normalize + gather out = v[x] ----------------
__global__ __launch_bounds__(256) void norm_gather(const unsigned short* __restrict__ H,
    const int* __restrict__ x, float* __restrict__ out)
{
  int row = blockIdx.x*4 + (threadIdx.x >> 6);
  if (row >= BT) return;
  int lane = threadIdx.x & 63;
  unsigned xi = (unsigned)x[row];
  unsigned hv = *(const unsigned*)(H + xi*128u + (unsigned)(lane*2));
  float v0 = lo16f(hv), v1 = hi16f(hv);
  float ss = v0*v0 + v1*v1;
  #pragma unroll
  for (int m = 32; m; m >>= 1) ss += __shfl_xor(ss, m, 64);
  float sc = 1.f / fmaxf(sqrtf(ss), 1e-5f);
  int d = lane*2;
  out[(size_t)row*128 + d]     = v0*sc;
  out[(size_t)row*128 + d + 1] = v1*sc;
}

extern "C" void kernel_launch(void* const* d_in, const int* in_sizes, int n_in,
                              void* d_out, int out_size, void* d_ws, size_t ws_size,
                              hipStream_t stream)
{
  const float* emb = (const float*)d_in[0];
  const float* W0  = (const float*)d_in[1];
  const float* al0 = (const float*)d_in[2];
  const float* ar0 = (const float*)d_in[3];
  const float* b0  = (const float*)d_in[4];
  const float* W1  = (const float*)d_in[5];
  const float* al1 = (const float*)d_in[6];
  const float* ar1 = (const float*)d_in[7];
  const float* b1  = (const float*)d_in[8];
  const int* n_feat = (const int*)d_in[9];
  const int* srcv = (const int*)d_in[10];
  const int* dstv = (const int*)d_in[11];
  const int* xv   = (const int*)d_in[12];
  float* out = (float*)d_out;

  char* p = (char*)d_ws;
  auto alloc = [&](size_t b)->char*{ char* q = p; p += (b + 255) & ~(size_t)255; return q; };
  unsigned short* Z   = (unsigned short*)alloc((size_t)N_NODES*128*2);
  unsigned short* H1b = (unsigned short*)alloc((size_t)N_NODES*128*2);  // layer0 out, layer1 in/out
  unsigned short* Hb0 = (unsigned short*)alloc((size_t)N_NODES*128*2);  // bf16 gathered emb rows
  int* offs  = (int*)alloc((size_t)(N_NODES+1)*4);
  int* csr   = (int*)alloc((size_t)N_EDGES*4);
  unsigned* ebuf = (unsigned*)alloc((size_t)N_EDGES*4);  // dead after p2fine; reused for el/er
  int* bh    = (int*)alloc((size_t)NBKT*NCHUNK*4);
  int* bsum  = (int*)alloc(256*4);
  unsigned short* Wt0 = (unsigned short*)alloc(128*128*2);
  unsigned short* Wt1 = (unsigned short*)alloc(128*128*2);
  float* el = (float*)ebuf;                              // N*8 floats
  float* er = el + (size_t)N_NODES*8;                    // N*8 floats (2*N*8*4 == E*4)

  const int NSCAN = NBKT*NCHUNK;                         // 57344

  // CSR build (no global atomics)
  p1hist<<<NCHUNK, 256, 0, stream>>>(dstv, bh);
  scan_partial<<<NSCAN/256, 256, 0, stream>>>(bh, bh, bsum, NSCAN);
  scan_add2<<<NSCAN/256, 256, 0, stream>>>(bh, bsum, NSCAN/256, NSCAN);
  p1scat<<<NCHUNK, 256, 0, stream>>>(srcv, dstv, bh, ebuf);
  p2fine<<<NBKT, 256, 0, stream>>>(ebuf, bh, offs, csr);

  twt_kernel<<<128, 256, 0, stream>>>(W0, W1, Wt0, Wt1);

  int gemm_grid = (N_NODES + 63)/64;
  int agg_grid  = (N_NODES + 3)/4;

  // layer 0 (rows gathered emb[n_feat] -> also Hb0; activation on)
  gemm_nt<0><<<gemm_grid, 256, 0, stream>>>(emb, n_feat, Wt0, al0, ar0, Z, el, er, Hb0);
  edge_agg<<<agg_grid, 256, 0, stream>>>(Z, el, er, offs, csr, Hb0, b0, H1b, 1);
  // layer 1 (bf16 input; in-place residual safe: wave reads row n before writing it)
  gemm_nt<1><<<gemm_grid, 256, 0, stream>>>(H1b, nullptr, Wt1, al1, ar1, Z, el, er, nullptr);
  edge_agg<<<agg_grid, 256, 0, stream>>>(Z, el, er, offs, csr, H1b, b1, H1b, 0);
  // normalize + output gather
  norm_gather<<<(BT + 3)/4, 256, 0, stream>>>(H1b, xv, out);
}